// Round 5
// baseline (1638.133 us; speedup 1.0000x reference)
//
#include <hip/hip_runtime.h>
#include <hip/hip_bf16.h>
#include <math.h>

#define B_ 128
#define S_ 100
#define W_ 20
#define D_ 192
#define L_ 6
#define H_ 8
#define DFF_ 256
#define DH_ 24
#define BS_ (B_*S_)
#define THREED_ 576

typedef short short8 __attribute__((ext_vector_type(8)));
typedef short short4v __attribute__((ext_vector_type(4)));
typedef float floatx16 __attribute__((ext_vector_type(16)));

__device__ __forceinline__ float posenc(int s, int c) {
  float freq = expf(-logf(10000.f) * (float)(2 * (c >> 1)) / (float)D_);
  float ang = (float)s * freq;
  return (c & 1) ? cosf(ang) : sinf(ang);
}

// 8B-aligned bf16x8 LDS load (for pitches that are 8- but not 16-byte aligned rows)
__device__ __forceinline__ short8 ld_frag8(const __hip_bfloat16* p) {
  short4v lo = *(const short4v*)p;
  short4v hi = *(const short4v*)(p + 4);
  short8 r;
  r[0]=lo[0]; r[1]=lo[1]; r[2]=lo[2]; r[3]=lo[3];
  r[4]=hi[0]; r[5]=hi[1]; r[6]=hi[2]; r[7]=hi[3];
  return r;
}

// ---------------------------------------------------------------------------
// Combined fp32->bf16 weight conversion. Segments (2048 elems/block):
// qkv_w 663552 (324 blk) | out_w 221184 (108) | ff1_w 294912 (144) |
// ff2_w 294912 (144) | wfuse_w 16384 (8). Grid = 728.
// ---------------------------------------------------------------------------
__global__ __launch_bounds__(256)
void convert5_kernel(const float* __restrict__ s0, __hip_bfloat16* __restrict__ d0,
                     const float* __restrict__ s1, __hip_bfloat16* __restrict__ d1,
                     const float* __restrict__ s2, __hip_bfloat16* __restrict__ d2,
                     const float* __restrict__ s3, __hip_bfloat16* __restrict__ d3,
                     const float* __restrict__ s4, __hip_bfloat16* __restrict__ d4)
{
  int b = blockIdx.x;
  const float* s; __hip_bfloat16* d; int base;
  if      (b < 324) { s = s0; d = d0; base = b; }
  else if (b < 432) { s = s1; d = d1; base = b - 324; }
  else if (b < 576) { s = s2; d = d2; base = b - 432; }
  else if (b < 720) { s = s3; d = d3; base = b - 576; }
  else              { s = s4; d = d4; base = b - 720; }
  int i = (base * 256 + threadIdx.x) * 8;
  float4 v0 = *(const float4*)(s + i);
  float4 v1 = *(const float4*)(s + i + 4);
  __hip_bfloat162* d2p = (__hip_bfloat162*)(d + i);
  d2p[0] = __float22bfloat162_rn(make_float2(v0.x, v0.y));
  d2p[1] = __float22bfloat162_rn(make_float2(v0.z, v0.w));
  d2p[2] = __float22bfloat162_rn(make_float2(v1.x, v1.y));
  d2p[3] = __float22bfloat162_rn(make_float2(v1.z, v1.w));
}

// ---------------------------------------------------------------------------
// qkv GEMM (bf16 MFMA): C(M,576) = A(M,192) @ W(576,192)^T + bias, bf16 out.
// 128 threads = 2 waves; BM=128, BN=64, BK=32. (validated in R3)
// ---------------------------------------------------------------------------
__global__ __launch_bounds__(128)
void qkv_gemm_kernel(const __hip_bfloat16* __restrict__ A,
                     const __hip_bfloat16* __restrict__ W,
                     const float* __restrict__ bias,
                     __hip_bfloat16* __restrict__ Cb)
{
  const int N = THREED_, K = D_;
  __shared__ __align__(16) __hip_bfloat16 Asl[128 * 40];
  __shared__ __align__(16) __hip_bfloat16 Bsl[64 * 40];
  int tid = threadIdx.x, lane = tid & 63, wv = tid >> 6;
  int bm = blockIdx.y * 128, bn = blockIdx.x * 64;
  int m32 = lane & 31, half = lane >> 5;

  floatx16 acc[2][2];
  #pragma unroll
  for (int mt = 0; mt < 2; ++mt)
    #pragma unroll
    for (int nt = 0; nt < 2; ++nt)
      #pragma unroll
      for (int r = 0; r < 16; ++r) acc[mt][nt][r] = 0.f;

  for (int k0 = 0; k0 < K; k0 += 32) {
    {
      const float4* src = (const float4*)(A + (size_t)(bm + tid) * K + k0);
      float4* dst = (float4*)&Asl[tid * 40];
      dst[0] = src[0]; dst[1] = src[1]; dst[2] = src[2]; dst[3] = src[3];
    }
    {
      int r = tid >> 1, h = tid & 1;
      const float4* src = (const float4*)(W + (size_t)(bn + r) * K + k0 + h * 16);
      float4* dst = (float4*)&Bsl[r * 40 + h * 16];
      dst[0] = src[0]; dst[1] = src[1];
    }
    __syncthreads();
    #pragma unroll
    for (int kc = 0; kc < 2; ++kc) {
      int ko = kc * 16 + half * 8;
      short8 a0 = *(const short8*)&Asl[(wv * 64 + m32) * 40 + ko];
      short8 a1 = *(const short8*)&Asl[(wv * 64 + 32 + m32) * 40 + ko];
      short8 b0 = *(const short8*)&Bsl[m32 * 40 + ko];
      short8 b1 = *(const short8*)&Bsl[(32 + m32) * 40 + ko];
      acc[0][0] = __builtin_amdgcn_mfma_f32_32x32x16_bf16(a0, b0, acc[0][0], 0, 0, 0);
      acc[0][1] = __builtin_amdgcn_mfma_f32_32x32x16_bf16(a0, b1, acc[0][1], 0, 0, 0);
      acc[1][0] = __builtin_amdgcn_mfma_f32_32x32x16_bf16(a1, b0, acc[1][0], 0, 0, 0);
      acc[1][1] = __builtin_amdgcn_mfma_f32_32x32x16_bf16(a1, b1, acc[1][1], 0, 0, 0);
    }
    __syncthreads();
  }

  float bb[2] = { bias[bn + m32], bias[bn + 32 + m32] };
  #pragma unroll
  for (int mt = 0; mt < 2; ++mt) {
    int rowbase = bm + wv * 64 + mt * 32 + 4 * half;
    #pragma unroll
    for (int nt = 0; nt < 2; ++nt) {
      int col = bn + nt * 32 + m32;
      #pragma unroll
      for (int r = 0; r < 16; ++r) {
        int row = rowbase + (r & 3) + 8 * (r >> 2);
        Cb[(size_t)row * N + col] = __float2bfloat16(acc[mt][nt][r] + bb[nt]);
      }
    }
  }
}

// ---------------------------------------------------------------------------
// out-proj + residual + LayerNorm, fused MFMA kernel.
// 256 threads = 4 waves. BM=128 (wave owns m-tile w), N=192 (all 6 n-tiles
// per wave -> full row in-wave => LN via shfl_xor over the 32-lane group).
// x (fp32) updated in place; xb bf16 mirror written.
// ---------------------------------------------------------------------------
__global__ __launch_bounds__(256)
void outln_kernel(const __hip_bfloat16* __restrict__ A,   // attb, K=192
                  const __hip_bfloat16* __restrict__ Wt,  // 192x192
                  const float* __restrict__ bias,
                  const float* __restrict__ g, const float* __restrict__ bvec,
                  float* __restrict__ x, __hip_bfloat16* __restrict__ xb)
{
  __shared__ __align__(16) __hip_bfloat16 Asl[128 * 40];
  __shared__ __align__(16) __hip_bfloat16 Bsl[192 * 40];
  int tid = threadIdx.x, lane = tid & 63, w = tid >> 6;
  int m32 = lane & 31, half = lane >> 5;
  int bm = blockIdx.x * 128;

  floatx16 acc[6];
  #pragma unroll
  for (int nt = 0; nt < 6; ++nt)
    #pragma unroll
    for (int r = 0; r < 16; ++r) acc[nt][r] = 0.f;

  for (int k0 = 0; k0 < D_; k0 += 32) {
    {
      int r = tid >> 1, h = tid & 1;
      const float4* s = (const float4*)(A + (size_t)(bm + r) * D_ + k0 + h * 16);
      float4* d = (float4*)&Asl[r * 40 + h * 16];
      d[0] = s[0]; d[1] = s[1];
    }
    for (int e = tid; e < 384; e += 256) {
      int r = e >> 1, h = e & 1;
      const float4* s = (const float4*)(Wt + (size_t)r * D_ + k0 + h * 16);
      float4* d = (float4*)&Bsl[r * 40 + h * 16];
      d[0] = s[0]; d[1] = s[1];
    }
    __syncthreads();
    #pragma unroll
    for (int kc = 0; kc < 2; ++kc) {
      int ko = kc * 16 + half * 8;
      short8 a = *(const short8*)&Asl[(w * 32 + m32) * 40 + ko];
      #pragma unroll
      for (int nt = 0; nt < 6; ++nt) {
        short8 b = *(const short8*)&Bsl[(nt * 32 + m32) * 40 + ko];
        acc[nt] = __builtin_amdgcn_mfma_f32_32x32x16_bf16(a, b, acc[nt], 0, 0, 0);
      }
    }
    __syncthreads();
  }

  // epilogue: residual + LN fully in-wave (each wave has full rows)
  float cbias[6], cg[6], cb2[6];
  #pragma unroll
  for (int nt = 0; nt < 6; ++nt) {
    int col = nt * 32 + m32;
    cbias[nt] = bias[col]; cg[nt] = g[col]; cb2[nt] = bvec[col];
  }
  int rowbase = bm + w * 32 + 4 * half;
  #pragma unroll
  for (int r = 0; r < 16; ++r) {
    int row = rowbase + (r & 3) + 8 * (r >> 2);
    float part = 0.f;
    #pragma unroll
    for (int nt = 0; nt < 6; ++nt) {
      int col = nt * 32 + m32;
      float t = acc[nt][r] + cbias[nt] + x[(size_t)row * D_ + col];
      acc[nt][r] = t;
      part += t;
    }
    #pragma unroll
    for (int off = 16; off; off >>= 1) part += __shfl_xor(part, off);
    float mean = part * (1.f / (float)D_);
    float sq = 0.f;
    #pragma unroll
    for (int nt = 0; nt < 6; ++nt) { float dd = acc[nt][r] - mean; sq += dd * dd; }
    #pragma unroll
    for (int off = 16; off; off >>= 1) sq += __shfl_xor(sq, off);
    float inv = rsqrtf(sq * (1.f / (float)D_) + 1e-5f);
    #pragma unroll
    for (int nt = 0; nt < 6; ++nt) {
      int col = nt * 32 + m32;
      float o = (acc[nt][r] - mean) * inv * cg[nt] + cb2[nt];
      x[(size_t)row * D_ + col] = o;
      xb[(size_t)row * D_ + col] = __float2bfloat16(o);
    }
  }
}

// ---------------------------------------------------------------------------
// ff1 + ff2 + residual + LayerNorm, fused. 256 threads = 4 waves, BM=64.
// ff1: M-tiles 2 x N-tiles 8 (wave: mt=w&1, ntiles (w>>1)*4..+3), relu out
// kept in LDS C1 (bf16, pitch 260 -> 2-way-free banks, 8B-aligned rows).
// ff2: A-frags read directly from C1; N=192 (wave: 3 n-tiles). LN stats
// combined across the 2 waves sharing an m-tile via psum/psq LDS.
// ---------------------------------------------------------------------------
__global__ __launch_bounds__(256)
void ffln_kernel(const __hip_bfloat16* __restrict__ xbi,
                 const __hip_bfloat16* __restrict__ W1, const float* __restrict__ b1,
                 const __hip_bfloat16* __restrict__ W2, const float* __restrict__ b2,
                 const float* __restrict__ g, const float* __restrict__ bvec,
                 float* __restrict__ x, __hip_bfloat16* __restrict__ xb)
{
  __shared__ __align__(16) __hip_bfloat16 C1[64 * 260];    // 33280 B
  __shared__ __align__(16) __hip_bfloat16 Asl[64 * 40];    // 5120
  __shared__ __align__(16) __hip_bfloat16 Bsl[256 * 40];   // 20480
  __shared__ float psum[64][2];
  __shared__ float psq[64][2];
  int tid = threadIdx.x, lane = tid & 63, w = tid >> 6;
  int m32 = lane & 31, half = lane >> 5;
  int mt = w & 1, ng = w >> 1;
  int bm = blockIdx.x * 64;

  // ---- ff1 ----
  floatx16 acc1[4];
  #pragma unroll
  for (int j = 0; j < 4; ++j)
    #pragma unroll
    for (int r = 0; r < 16; ++r) acc1[j][r] = 0.f;

  for (int k0 = 0; k0 < D_; k0 += 32) {
    if (tid < 128) {
      int r = tid >> 1, h = tid & 1;
      const float4* s = (const float4*)(xbi + (size_t)(bm + r) * D_ + k0 + h * 16);
      float4* d = (float4*)&Asl[r * 40 + h * 16];
      d[0] = s[0]; d[1] = s[1];
    }
    for (int e = tid; e < 512; e += 256) {
      int r = e >> 1, h = e & 1;
      const float4* s = (const float4*)(W1 + (size_t)r * D_ + k0 + h * 16);
      float4* d = (float4*)&Bsl[r * 40 + h * 16];
      d[0] = s[0]; d[1] = s[1];
    }
    __syncthreads();
    #pragma unroll
    for (int kc = 0; kc < 2; ++kc) {
      int ko = kc * 16 + half * 8;
      short8 a = *(const short8*)&Asl[(mt * 32 + m32) * 40 + ko];
      #pragma unroll
      for (int j = 0; j < 4; ++j) {
        short8 b = *(const short8*)&Bsl[((ng * 4 + j) * 32 + m32) * 40 + ko];
        acc1[j] = __builtin_amdgcn_mfma_f32_32x32x16_bf16(a, b, acc1[j], 0, 0, 0);
      }
    }
    __syncthreads();
  }
  {
    int rowb = mt * 32 + 4 * half;
    #pragma unroll
    for (int j = 0; j < 4; ++j) {
      int col = (ng * 4 + j) * 32 + m32;
      float cb = b1[col];
      #pragma unroll
      for (int r = 0; r < 16; ++r) {
        int row = rowb + (r & 3) + 8 * (r >> 2);
        C1[row * 260 + col] = __float2bfloat16(fmaxf(acc1[j][r] + cb, 0.f));
      }
    }
  }
  __syncthreads();

  // ---- ff2 ----
  floatx16 acc2[3];
  #pragma unroll
  for (int j = 0; j < 3; ++j)
    #pragma unroll
    for (int r = 0; r < 16; ++r) acc2[j][r] = 0.f;

  for (int k0 = 0; k0 < DFF_; k0 += 32) {
    for (int e = tid; e < 384; e += 256) {
      int r = e >> 1, h = e & 1;
      const float4* s = (const float4*)(W2 + (size_t)r * DFF_ + k0 + h * 16);
      float4* d = (float4*)&Bsl[r * 40 + h * 16];
      d[0] = s[0]; d[1] = s[1];
    }
    __syncthreads();
    #pragma unroll
    for (int kc = 0; kc < 2; ++kc) {
      int ko = kc * 16 + half * 8;
      short8 a = ld_frag8(&C1[(mt * 32 + m32) * 260 + k0 + ko]);
      #pragma unroll
      for (int j = 0; j < 3; ++j) {
        short8 b = *(const short8*)&Bsl[((ng * 3 + j) * 32 + m32) * 40 + ko];
        acc2[j] = __builtin_amdgcn_mfma_f32_32x32x16_bf16(a, b, acc2[j], 0, 0, 0);
      }
    }
    __syncthreads();
  }

  // ---- epilogue: residual + LN with cross-wave stats ----
  int rowb = mt * 32 + 4 * half;
  #pragma unroll
  for (int r = 0; r < 16; ++r) {
    int rl = rowb + (r & 3) + 8 * (r >> 2);
    int row = bm + rl;
    float p = 0.f;
    #pragma unroll
    for (int j = 0; j < 3; ++j) {
      int col = (ng * 3 + j) * 32 + m32;
      float t = acc2[j][r] + b2[col] + x[(size_t)row * D_ + col];
      acc2[j][r] = t;
      p += t;
    }
    #pragma unroll
    for (int off = 16; off; off >>= 1) p += __shfl_xor(p, off);
    if (m32 == 0) psum[rl][ng] = p;
  }
  __syncthreads();
  float mean[16];
  #pragma unroll
  for (int r = 0; r < 16; ++r) {
    int rl = rowb + (r & 3) + 8 * (r >> 2);
    mean[r] = (psum[rl][0] + psum[rl][1]) * (1.f / (float)D_);
  }
  #pragma unroll
  for (int r = 0; r < 16; ++r) {
    int rl = rowb + (r & 3) + 8 * (r >> 2);
    float s = 0.f;
    #pragma unroll
    for (int j = 0; j < 3; ++j) { float dd = acc2[j][r] - mean[r]; s += dd * dd; }
    #pragma unroll
    for (int off = 16; off; off >>= 1) s += __shfl_xor(s, off);
    if (m32 == 0) psq[rl][ng] = s;
  }
  __syncthreads();
  #pragma unroll
  for (int r = 0; r < 16; ++r) {
    int rl = rowb + (r & 3) + 8 * (r >> 2);
    int row = bm + rl;
    float inv = rsqrtf((psq[rl][0] + psq[rl][1]) * (1.f / (float)D_) + 1e-5f);
    #pragma unroll
    for (int j = 0; j < 3; ++j) {
      int col = (ng * 3 + j) * 32 + m32;
      float o = (acc2[j][r] - mean[r]) * inv * g[col] + bvec[col];
      x[(size_t)row * D_ + col] = o;
      xb[(size_t)row * D_ + col] = __float2bfloat16(o);
    }
  }
}

// ---------------------------------------------------------------------------
// MFMA encoder: 8 bs (160 (bs,w) rows) per block, 256 threads = 4 waves.
// wcomb built as bf16 in LDS (pitch 132 -> 2-way-free banks), wfuse GEMM on
// MFMA (5 m-tiles x 4 n-tiles, K=128), masked-avg epilogue via LDS atomics.
// ---------------------------------------------------------------------------
__global__ __launch_bounds__(256)
void encode_mfma_kernel(
    const int* __restrict__ title_idx, const int* __restrict__ class_idx,
    const int* __restrict__ process_idx, const int* __restrict__ activity_type,
    const float* __restrict__ mouse_pos, const float* __restrict__ rect,
    const float* __restrict__ flags, const float* __restrict__ keyboard_active,
    const float* __restrict__ window_mask,
    const float* __restrict__ title_emb, const float* __restrict__ class_emb,
    const float* __restrict__ process_emb,
    const float* __restrict__ sw1, const float* __restrict__ sb1,
    const float* __restrict__ sw2, const float* __restrict__ sb2,
    const __hip_bfloat16* __restrict__ wfwb, const float* __restrict__ wfb,
    const float* __restrict__ mw1, const float* __restrict__ mb1,
    const float* __restrict__ mw2, const float* __restrict__ mb2,
    const float* __restrict__ act_emb, const float* __restrict__ kbw,
    const float* __restrict__ kbb,
    const float* __restrict__ afw, const float* __restrict__ afb,
    float* __restrict__ x, __hip_bfloat16* __restrict__ xb)
{
  __shared__ __align__(16) __hip_bfloat16 Awc[160 * 132];  // 42240 B
  __shared__ __align__(16) __hip_bfloat16 Bsl[128 * 40];   // 10240
  __shared__ float avgS[8 * 132];                          // 4224
  __shared__ float scratch[1088];                          // hidS / afA+afB  4352
  __shared__ float maskS[160];                             // 640

  int tid = threadIdx.x;
  int tx = tid & 15, ty = tid >> 4;
  int bs0 = blockIdx.x * 8;
  int row0 = bs0 * W_;

  // phase 0: mask + avg zero
  for (int e = tid; e < 160; e += 256) maskS[e] = window_mask[row0 + e];
  for (int e = tid; e < 8 * 132; e += 256) avgS[e] = 0.f;

  // phase 1a: embedding gathers -> Awc[:, 0:96] (bf16)
  for (int idx = tid; idx < 160 * 96; idx += 256) {
    int r = idx / 96, c = idx - r * 96;
    int rg = row0 + r;
    float v;
    if (c < 32)      v = title_emb[title_idx[rg] * 32 + c];
    else if (c < 64) v = class_emb[class_idx[rg] * 32 + (c - 32)];
    else             v = process_emb[process_idx[rg] * 32 + (c - 64)];
    Awc[r * 132 + c] = __float2bfloat16(v);
  }

  // phase 1b: spatial MLP -> Awc[:, 96:128], 10 chunks of 16 rows
  float* hidS = scratch;   // [16][68]
  for (int chunk = 0; chunk < 10; ++chunk) {
    int r = chunk * 16 + ty;
    int rg = row0 + r;
    float4 rc = *(const float4*)(rect + (size_t)rg * 4);
    float f0 = flags[rg * 2], f1 = flags[rg * 2 + 1];
    __syncthreads();
    #pragma unroll
    for (int u = 0; u < 4; ++u) {
      int cc = tx + 16 * u;
      const float* w1 = sw1 + cc * 6;
      float a = sb1[cc] + w1[0]*rc.x + w1[1]*rc.y + w1[2]*rc.z + w1[3]*rc.w
                        + w1[4]*f0 + w1[5]*f1;
      hidS[ty * 68 + cc] = fmaxf(a, 0.f);
    }
    __syncthreads();
    #pragma unroll
    for (int v2 = 0; v2 < 2; ++v2) {
      int cc = tx + 16 * v2;
      const float4* w2 = (const float4*)(sw2 + cc * 64);
      const float4* hp = (const float4*)&hidS[ty * 68];
      float a = sb2[cc];
      #pragma unroll
      for (int k4 = 0; k4 < 16; ++k4) {
        float4 ww = w2[k4], h = hp[k4];
        a += ww.x*h.x + ww.y*h.y + ww.z*h.z + ww.w*h.w;
      }
      Awc[r * 132 + 96 + cc] = __float2bfloat16(a);
    }
  }
  __syncthreads();

  // phase 2: MFMA GEMM  C[160x128] = Awc @ wfw^T, masked-avg epilogue
  int lane = tid & 63, w = tid >> 6;
  int m32 = lane & 31, half = lane >> 5;
  floatx16 acc[5];
  #pragma unroll
  for (int mt = 0; mt < 5; ++mt)
    #pragma unroll
    for (int r = 0; r < 16; ++r) acc[mt][r] = 0.f;

  for (int kt = 0; kt < 4; ++kt) {
    int k0 = kt * 32;
    {
      int r = tid >> 1, h = tid & 1;
      const float4* s = (const float4*)(wfwb + (size_t)r * 128 + k0 + h * 16);
      float4* d = (float4*)&Bsl[r * 40 + h * 16];
      d[0] = s[0]; d[1] = s[1];
    }
    __syncthreads();
    #pragma unroll
    for (int kc = 0; kc < 2; ++kc) {
      int ko = kc * 16 + half * 8;
      short8 b = *(const short8*)&Bsl[(w * 32 + m32) * 40 + ko];
      #pragma unroll
      for (int mt = 0; mt < 5; ++mt) {
        short8 a = ld_frag8(&Awc[(mt * 32 + m32) * 132 + k0 + ko]);
        acc[mt] = __builtin_amdgcn_mfma_f32_32x32x16_bf16(a, b, acc[mt], 0, 0, 0);
      }
    }
    __syncthreads();
  }
  {
    int col = w * 32 + m32;
    float cb = wfb[col];
    #pragma unroll
    for (int mt = 0; mt < 5; ++mt) {
      int rowb = mt * 32 + 4 * half;
      #pragma unroll
      for (int r = 0; r < 16; ++r) {
        int row = rowb + (r & 3) + 8 * (r >> 2);
        float val = fmaxf(acc[mt][r] + cb, 0.f) * maskS[row];
        atomicAdd(&avgS[(row / 20) * 132 + col], val);
      }
    }
  }
  __syncthreads();

  // x[:, 0:128] = avg + posenc
  for (int e = tid; e < 8 * 128; e += 256) {
    int bsl = e >> 7, col = e & 127;
    int bsg = bs0 + bsl;
    float v = avgS[bsl * 132 + col] * (1.f / (float)W_) + posenc(bsg % S_, col);
    x[(size_t)bsg * D_ + col] = v;
    xb[(size_t)bsg * D_ + col] = __float2bfloat16(v);
  }

  // phase 3: activity fusion -> x[:, 128:192], 2 passes of 4 bs
  float* afA = scratch;            // [4][68]
  float* afB = scratch + 4 * 68;   // [4][68]
  for (int pass = 0; pass < 2; ++pass) {
    int bl = tid >> 6, ln = tid & 63;
    int bsg = bs0 + pass * 4 + bl;
    __syncthreads();
    if (ln < 32) {
      float mx = mouse_pos[bsg * 2 + 0] * (1.f / 1920.f);
      float my = mouse_pos[bsg * 2 + 1] * (1.f / 1080.f);
      afA[bl * 68 + ln] = fmaxf(mw1[ln * 2] * mx + mw1[ln * 2 + 1] * my + mb1[ln], 0.f);
    }
    __syncthreads();
    float cv;
    if (ln < 32) {
      float a = mb2[ln];
      #pragma unroll 8
      for (int k = 0; k < 32; ++k) a += mw2[ln * 32 + k] * afA[bl * 68 + k];
      cv = a;
    } else if (ln < 48) {
      cv = act_emb[activity_type[bsg] * 16 + (ln - 32)];
    } else {
      cv = kbw[ln - 48] * keyboard_active[bsg] + kbb[ln - 48];
    }
    __syncthreads();
    afB[bl * 68 + ln] = cv;
    __syncthreads();
    {
      float a = afb[ln];
      const float4* w4 = (const float4*)(afw + ln * 64);
      const float4* cp = (const float4*)&afB[bl * 68];
      #pragma unroll
      for (int k4 = 0; k4 < 16; ++k4) {
        float4 ww = w4[k4], c = cp[k4];
        a += ww.x*c.x + ww.y*c.y + ww.z*c.z + ww.w*c.w;
      }
      float v = fmaxf(a, 0.f);
      int cg = 128 + ln;
      float o = v + posenc(bsg % S_, cg);
      x[(size_t)bsg * D_ + cg] = o;
      xb[(size_t)bsg * D_ + cg] = __float2bfloat16(o);
    }
  }
}

// ---------------------------------------------------------------------------
// Attention: bf16 in/out, fp32 math. One block per (b,h), 256 threads.
// ---------------------------------------------------------------------------
__global__ __launch_bounds__(256)
void attn_kernel(const __hip_bfloat16* __restrict__ qkv, __hip_bfloat16* __restrict__ o)
{
  int bh = blockIdx.x;
  int hh = bh & 7, b = bh >> 3;
  int tid = threadIdx.x, wv = tid >> 6, ln = tid & 63;
  __shared__ float Qs[100 * 25];
  __shared__ float Ks[24 * 132];
  __shared__ float Vs[100 * 25];
  __shared__ float Ps[4 * 132];
  const __hip_bfloat16* base = qkv + (size_t)b * S_ * THREED_ + hh * DH_;
  for (int i = tid; i < 2400; i += 256) {
    int r = i / 24, d = i - r * 24;
    const __hip_bfloat16* rp = base + (size_t)r * THREED_;
    Qs[r * 25 + d]  = __bfloat162float(rp[d]);
    Ks[d * 132 + r] = __bfloat162float(rp[D_ + d]);
    Vs[r * 25 + d]  = __bfloat162float(rp[2 * D_ + d]);
  }
  __syncthreads();
  const float scale = 0.20412414523193154f;  // 1/sqrt(24)
  int k1 = ln + 64;
  bool k1v = (k1 < S_);
  for (int q = wv; q < S_; q += 4) {
    float s0 = 0.f, s1 = 0.f;
    #pragma unroll
    for (int d = 0; d < DH_; ++d) {
      float qd = Qs[q * 25 + d];
      s0 += qd * Ks[d * 132 + ln];
      s1 += qd * Ks[d * 132 + k1];
    }
    s0 *= scale;
    s1 = k1v ? s1 * scale : -1e30f;
    float mx = fmaxf(s0, s1);
    #pragma unroll
    for (int off = 32; off; off >>= 1) mx = fmaxf(mx, __shfl_xor(mx, off));
    float e0 = expf(s0 - mx);
    float e1 = k1v ? expf(s1 - mx) : 0.f;
    float sm = e0 + e1;
    #pragma unroll
    for (int off = 32; off; off >>= 1) sm += __shfl_xor(sm, off);
    float inv = 1.f / sm;
    Ps[wv * 132 + ln] = e0;
    if (k1v) Ps[wv * 132 + k1] = e1;
    float acc = 0.f;
    int d = ln % 24, g = ln / 24;
    if (ln < 48) {
      int kb = g * 50;
      for (int k = kb; k < kb + 50; ++k)
        acc += Ps[wv * 132 + k] * Vs[k * 25 + d];
    }
    float other = __shfl(acc, (ln + 24) & 63);
    if (ln < 24)
      o[((size_t)(b * S_ + q)) * D_ + hh * DH_ + ln] = __float2bfloat16((acc + other) * inv);
  }
}

// ---------------------------------------------------------------------------
// Head (fp32): one block per (w,b) slot.
// ---------------------------------------------------------------------------
__global__ __launch_bounds__(256)
void head_kernel(const float* __restrict__ x, const float* __restrict__ noise,
                 const float* __restrict__ pw1, const float* __restrict__ pb1,
                 const float* __restrict__ pw2, const float* __restrict__ pb2,
                 const float* __restrict__ ew1, const float* __restrict__ eb1,
                 const float* __restrict__ ew2, const float* __restrict__ eb2,
                 float* __restrict__ out)
{
  int idx = blockIdx.x;
  int b = idx & 127, w = idx >> 7;
  int tid = threadIdx.x;
  __shared__ float slot[192];
  __shared__ float ph[256];
  __shared__ float eh[128];
  if (tid < 192)
    slot[tid] = x[((size_t)b * S_ + (S_ - 1)) * D_ + tid]
              + noise[((size_t)w * B_ + b) * D_ + tid] * 0.1f;
  __syncthreads();
  {
    const float4* wr = (const float4*)(pw1 + (size_t)tid * D_);
    const float4* sp = (const float4*)slot;
    float a = pb1[tid];
    #pragma unroll 12
    for (int k = 0; k < 48; ++k) {
      float4 wv = wr[k], sv = sp[k];
      a += wv.x*sv.x + wv.y*sv.y + wv.z*sv.z + wv.w*sv.w;
    }
    ph[tid] = fmaxf(a, 0.f);
  }
  if (tid < 128) {
    const float4* wr = (const float4*)(ew1 + (size_t)tid * D_);
    const float4* sp = (const float4*)slot;
    float a = eb1[tid];
    #pragma unroll 12
    for (int k = 0; k < 48; ++k) {
      float4 wv = wr[k], sv = sp[k];
      a += wv.x*sv.x + wv.y*sv.y + wv.z*sv.z + wv.w*sv.w;
    }
    eh[tid] = fmaxf(a, 0.f);
  }
  __syncthreads();
  if (tid < 4) {
    float a = pb2[tid];
    const float4* wr = (const float4*)(pw2 + tid * 256);
    const float4* pp = (const float4*)ph;
    for (int k = 0; k < 64; ++k) {
      float4 wv = wr[k], pv = pp[k];
      a += wv.x*pv.x + wv.y*pv.y + wv.z*pv.z + wv.w*pv.w;
    }
    out[((size_t)b * W_ + w) * 4 + tid] = a;
  }
  if (tid == 4) {
    float a = eb2[0];
    const float4* wr = (const float4*)ew2;
    const float4* pp = (const float4*)eh;
    for (int k = 0; k < 32; ++k) {
      float4 wv = wr[k], pv = pp[k];
      a += wv.x*pv.x + wv.y*pv.y + wv.z*pv.z + wv.w*pv.w;
    }
    out[(size_t)B_ * W_ * 4 + (size_t)b * W_ + w] = 1.f / (1.f + expf(-a));
  }
}

// ---------------------------------------------------------------------------
extern "C" void kernel_launch(void* const* d_in, const int* in_sizes, int n_in,
                              void* d_out, int out_size, void* d_ws, size_t ws_size,
                              hipStream_t stream)
{
  const int*   title_idx       = (const int*)  d_in[0];
  const int*   class_idx       = (const int*)  d_in[1];
  const int*   process_idx     = (const int*)  d_in[2];
  const int*   activity_type   = (const int*)  d_in[3];
  const float* mouse_pos       = (const float*)d_in[4];
  const float* rect            = (const float*)d_in[5];
  const float* flags           = (const float*)d_in[6];
  const float* keyboard_active = (const float*)d_in[7];
  const float* window_mask     = (const float*)d_in[8];
  const float* noise           = (const float*)d_in[9];
  const float* title_emb       = (const float*)d_in[10];
  const float* class_emb       = (const float*)d_in[11];
  const float* process_emb     = (const float*)d_in[12];
  const float* spatial_w1      = (const float*)d_in[13];
  const float* spatial_b1      = (const float*)d_in[14];
  const float* spatial_w2      = (const float*)d_in[15];
  const float* spatial_b2      = (const float*)d_in[16];
  const float* wfuse_w         = (const float*)d_in[17];
  const float* wfuse_b         = (const float*)d_in[18];
  const float* mouse_w1        = (const float*)d_in[19];
  const float* mouse_b1        = (const float*)d_in[20];
  const float* mouse_w2        = (const float*)d_in[21];
  const float* mouse_b2        = (const float*)d_in[22];
  const float* act_emb         = (const float*)d_in[23];
  const float* kbd_w           = (const float*)d_in[24];
  const float* kbd_b           = (const float*)d_in[25];
  const float* afuse_w         = (const float*)d_in[26];
  const float* afuse_b         = (const float*)d_in[27];
  const float* qkv_w           = (const float*)d_in[28];
  const float* qkv_b           = (const float*)d_in[29];
  const float* out_w           = (const float*)d_in[30];
  const float* out_b           = (const float*)d_in[31];
  const float* ff1_w           = (const float*)d_in[32];
  const float* ff1_b           = (const float*)d_in[33];
  const float* ff2_w           = (const float*)d_in[34];
  const float* ff2_b           = (const float*)d_in[35];
  const float* ln1_g           = (const float*)d_in[36];
  const float* ln1_b           = (const float*)d_in[37];
  const float* ln2_g           = (const float*)d_in[38];
  const float* ln2_b           = (const float*)d_in[39];
  const float* proj_w1         = (const float*)d_in[40];
  const float* proj_b1         = (const float*)d_in[41];
  const float* proj_w2         = (const float*)d_in[42];
  const float* proj_b2         = (const float*)d_in[43];
  const float* ex_w1           = (const float*)d_in[44];
  const float* ex_b1           = (const float*)d_in[45];
  const float* ex_w2           = (const float*)d_in[46];
  const float* ex_b2           = (const float*)d_in[47];

  float* out = (float*)d_out;

  // workspace layout
  float* x = (float*)d_ws;                                      // BS*192 f32
  __hip_bfloat16* xb   = (__hip_bfloat16*)(x + (size_t)BS_ * D_);
  __hip_bfloat16* qkvb = xb   + (size_t)BS_ * D_;
  __hip_bfloat16* attb = qkvb + (size_t)BS_ * THREED_;
  __hip_bfloat16* wqb  = attb + (size_t)BS_ * D_;               // 6*576*192
  __hip_bfloat16* wob  = wqb  + (size_t)L_ * THREED_ * D_;      // 6*192*192
  __hip_bfloat16* wf1b = wob  + (size_t)L_ * D_ * D_;           // 6*256*192
  __hip_bfloat16* wf2b = wf1b + (size_t)L_ * DFF_ * D_;         // 6*192*256
  __hip_bfloat16* wfwb = wf2b + (size_t)L_ * D_ * DFF_;         // 128*128
  (void)ws_size; (void)n_in; (void)in_sizes; (void)out_size;

  // single combined weight conversion
  convert5_kernel<<<728, 256, 0, stream>>>(qkv_w, wqb, out_w, wob,
                                           ff1_w, wf1b, ff2_w, wf2b,
                                           wfuse_w, wfwb);

  // encoder (MFMA)
  encode_mfma_kernel<<<BS_ / 8, 256, 0, stream>>>(
      title_idx, class_idx, process_idx, activity_type, mouse_pos, rect, flags,
      keyboard_active, window_mask, title_emb, class_emb, process_emb,
      spatial_w1, spatial_b1, spatial_w2, spatial_b2, wfwb, wfuse_b,
      mouse_w1, mouse_b1, mouse_w2, mouse_b2, act_emb, kbd_w, kbd_b,
      afuse_w, afuse_b, x, xb);

  // transformer layers: qkv -> attn -> out+LN -> ff+LN  (4 dispatches/layer)
  for (int l = 0; l < L_; ++l) {
    qkv_gemm_kernel<<<dim3(THREED_ / 64, BS_ / 128), 128, 0, stream>>>(
        xb, wqb + (size_t)l * THREED_ * D_, qkv_b + (size_t)l * THREED_, qkvb);
    attn_kernel<<<B_ * H_, 256, 0, stream>>>(qkvb, attb);
    outln_kernel<<<BS_ / 128, 256, 0, stream>>>(
        attb, wob + (size_t)l * D_ * D_, out_b + (size_t)l * D_,
        ln1_g + (size_t)l * D_, ln1_b + (size_t)l * D_, x, xb);
    ffln_kernel<<<BS_ / 64, 256, 0, stream>>>(
        xb, wf1b + (size_t)l * DFF_ * D_, ff1_b + (size_t)l * DFF_,
        wf2b + (size_t)l * D_ * DFF_, ff2_b + (size_t)l * D_,
        ln2_g + (size_t)l * D_, ln2_b + (size_t)l * D_, x, xb);
  }

  // head
  head_kernel<<<W_ * B_, 256, 0, stream>>>(
      x, noise, proj_w1, proj_b1, proj_w2, proj_b2,
      ex_w1, ex_b1, ex_w2, ex_b2, out);
}

// Round 6
// 1378.348 us; speedup vs baseline: 1.1885x; 1.1885x over previous
//
#include <hip/hip_runtime.h>
#include <hip/hip_bf16.h>
#include <math.h>

#define B_ 128
#define S_ 100
#define W_ 20
#define D_ 192
#define L_ 6
#define H_ 8
#define DFF_ 256
#define DH_ 24
#define BS_ (B_*S_)
#define THREED_ 576

typedef short short8 __attribute__((ext_vector_type(8)));
typedef short short4v __attribute__((ext_vector_type(4)));
typedef float floatx16 __attribute__((ext_vector_type(16)));

__device__ __forceinline__ float posenc(int s, int c) {
  float freq = expf(-logf(10000.f) * (float)(2 * (c >> 1)) / (float)D_);
  float ang = (float)s * freq;
  return (c & 1) ? cosf(ang) : sinf(ang);
}

// 8B-aligned bf16x8 LDS load
__device__ __forceinline__ short8 ld_frag8(const __hip_bfloat16* p) {
  short4v lo = *(const short4v*)p;
  short4v hi = *(const short4v*)(p + 4);
  short8 r;
  r[0]=lo[0]; r[1]=lo[1]; r[2]=lo[2]; r[3]=lo[3];
  r[4]=hi[0]; r[5]=hi[1]; r[6]=hi[2]; r[7]=hi[3];
  return r;
}

// ---------------------------------------------------------------------------
// Combined fp32->bf16 weight conversion (2048 elems/block). Grid = 728.
// ---------------------------------------------------------------------------
__global__ __launch_bounds__(256)
void convert5_kernel(const float* __restrict__ s0, __hip_bfloat16* __restrict__ d0,
                     const float* __restrict__ s1, __hip_bfloat16* __restrict__ d1,
                     const float* __restrict__ s2, __hip_bfloat16* __restrict__ d2,
                     const float* __restrict__ s3, __hip_bfloat16* __restrict__ d3,
                     const float* __restrict__ s4, __hip_bfloat16* __restrict__ d4)
{
  int b = blockIdx.x;
  const float* s; __hip_bfloat16* d; int base;
  if      (b < 324) { s = s0; d = d0; base = b; }
  else if (b < 432) { s = s1; d = d1; base = b - 324; }
  else if (b < 576) { s = s2; d = d2; base = b - 432; }
  else if (b < 720) { s = s3; d = d3; base = b - 576; }
  else              { s = s4; d = d4; base = b - 720; }
  int i = (base * 256 + threadIdx.x) * 8;
  float4 v0 = *(const float4*)(s + i);
  float4 v1 = *(const float4*)(s + i + 4);
  __hip_bfloat162* d2p = (__hip_bfloat162*)(d + i);
  d2p[0] = __float22bfloat162_rn(make_float2(v0.x, v0.y));
  d2p[1] = __float22bfloat162_rn(make_float2(v0.z, v0.w));
  d2p[2] = __float22bfloat162_rn(make_float2(v1.x, v1.y));
  d2p[3] = __float22bfloat162_rn(make_float2(v1.z, v1.w));
}

// ---------------------------------------------------------------------------
// qkv GEMM (bf16 MFMA, validated R3): C(M,576)=A(M,192)@W^T+bias, bf16 out.
// ---------------------------------------------------------------------------
__global__ __launch_bounds__(128)
void qkv_gemm_kernel(const __hip_bfloat16* __restrict__ A,
                     const __hip_bfloat16* __restrict__ W,
                     const float* __restrict__ bias,
                     __hip_bfloat16* __restrict__ Cb)
{
  const int N = THREED_, K = D_;
  __shared__ __align__(16) __hip_bfloat16 Asl[128 * 40];
  __shared__ __align__(16) __hip_bfloat16 Bsl[64 * 40];
  int tid = threadIdx.x, lane = tid & 63, wv = tid >> 6;
  int bm = blockIdx.y * 128, bn = blockIdx.x * 64;
  int m32 = lane & 31, half = lane >> 5;

  floatx16 acc[2][2];
  #pragma unroll
  for (int mt = 0; mt < 2; ++mt)
    #pragma unroll
    for (int nt = 0; nt < 2; ++nt)
      #pragma unroll
      for (int r = 0; r < 16; ++r) acc[mt][nt][r] = 0.f;

  for (int k0 = 0; k0 < K; k0 += 32) {
    {
      const float4* src = (const float4*)(A + (size_t)(bm + tid) * K + k0);
      float4* dst = (float4*)&Asl[tid * 40];
      dst[0] = src[0]; dst[1] = src[1]; dst[2] = src[2]; dst[3] = src[3];
    }
    {
      int r = tid >> 1, h = tid & 1;
      const float4* src = (const float4*)(W + (size_t)(bn + r) * K + k0 + h * 16);
      float4* dst = (float4*)&Bsl[r * 40 + h * 16];
      dst[0] = src[0]; dst[1] = src[1];
    }
    __syncthreads();
    #pragma unroll
    for (int kc = 0; kc < 2; ++kc) {
      int ko = kc * 16 + half * 8;
      short8 a0 = *(const short8*)&Asl[(wv * 64 + m32) * 40 + ko];
      short8 a1 = *(const short8*)&Asl[(wv * 64 + 32 + m32) * 40 + ko];
      short8 b0 = *(const short8*)&Bsl[m32 * 40 + ko];
      short8 b1 = *(const short8*)&Bsl[(32 + m32) * 40 + ko];
      acc[0][0] = __builtin_amdgcn_mfma_f32_32x32x16_bf16(a0, b0, acc[0][0], 0, 0, 0);
      acc[0][1] = __builtin_amdgcn_mfma_f32_32x32x16_bf16(a0, b1, acc[0][1], 0, 0, 0);
      acc[1][0] = __builtin_amdgcn_mfma_f32_32x32x16_bf16(a1, b0, acc[1][0], 0, 0, 0);
      acc[1][1] = __builtin_amdgcn_mfma_f32_32x32x16_bf16(a1, b1, acc[1][1], 0, 0, 0);
    }
    __syncthreads();
  }

  float bb[2] = { bias[bn + m32], bias[bn + 32 + m32] };
  #pragma unroll
  for (int mt = 0; mt < 2; ++mt) {
    int rowbase = bm + wv * 64 + mt * 32 + 4 * half;
    #pragma unroll
    for (int nt = 0; nt < 2; ++nt) {
      int col = bn + nt * 32 + m32;
      #pragma unroll
      for (int r = 0; r < 16; ++r) {
        int row = rowbase + (r & 3) + 8 * (r >> 2);
        Cb[(size_t)row * N + col] = __float2bfloat16(acc[mt][nt][r] + bb[nt]);
      }
    }
  }
}

// ---------------------------------------------------------------------------
// MFMA attention: one block per (b,h), 256 threads = 4 waves.
// S padded 100->128 (4 m-tiles of 32). QK^T: wave w owns q-rows 32w..32w+31,
// 4 n-tiles x 2 k-steps. Softmax in-register (rows complete within 32-lane
// groups of the C-layout). P stored bf16 to LDS in A-frag layout; PV reads V
// transposed (Vt[d][key]). Unnormalized PV, divide by row-sum at the end.
// LDS = 10240+10240+8704+34816 = 64000 B.
// ---------------------------------------------------------------------------
__global__ __launch_bounds__(256)
void attn_mfma_kernel(const __hip_bfloat16* __restrict__ qkv,
                      __hip_bfloat16* __restrict__ o)
{
  __shared__ __align__(16) __hip_bfloat16 Qs[128 * 40];
  __shared__ __align__(16) __hip_bfloat16 Ks[128 * 40];
  __shared__ __align__(16) __hip_bfloat16 Vt[32 * 136];
  __shared__ __align__(16) __hip_bfloat16 Ps[128 * 136];
  int bh = blockIdx.x;
  int hh = bh & 7, b = bh >> 3;
  int tid = threadIdx.x, lane = tid & 63, w = tid >> 6;
  int m32 = lane & 31, half = lane >> 5;
  const __hip_bfloat16* base = qkv + (size_t)b * S_ * THREED_ + hh * DH_;

  // zero Vt (pads: d>=24, key>=100)
  for (int e = tid; e < (32 * 136) / 8; e += 256)
    ((float4*)Vt)[e] = make_float4(0.f, 0.f, 0.f, 0.f);
  // stage Q,K rows (3x16B valid + 2x16B zero pad per row; pad rows zero)
  for (int e = tid; e < 1280; e += 256) {
    int mtx = e / 640;
    int rem = e - mtx * 640;
    int row = rem / 5, seg = rem - row * 5;
    float4 v = make_float4(0.f, 0.f, 0.f, 0.f);
    if (row < S_ && seg < 3)
      v = *(const float4*)(base + (size_t)row * THREED_ + mtx * D_ + seg * 8);
    __hip_bfloat16* dst = mtx ? Ks : Qs;
    *(float4*)&dst[row * 40 + seg * 8] = v;
  }
  __syncthreads();   // Vt zero done before scatter
  for (int i = tid; i < S_ * DH_; i += 256) {
    int key = i / DH_, d = i - key * DH_;
    Vt[d * 136 + key] = base[(size_t)key * THREED_ + 2 * D_ + d];
  }
  __syncthreads();

  // ---- QK^T ----
  floatx16 sc[4];
  #pragma unroll
  for (int nt = 0; nt < 4; ++nt)
    #pragma unroll
    for (int r = 0; r < 16; ++r) sc[nt][r] = 0.f;
  #pragma unroll
  for (int kc = 0; kc < 2; ++kc) {
    int ko = kc * 16 + half * 8;
    short8 a = *(const short8*)&Qs[(w * 32 + m32) * 40 + ko];
    #pragma unroll
    for (int nt = 0; nt < 4; ++nt) {
      short8 bf = *(const short8*)&Ks[(nt * 32 + m32) * 40 + ko];
      sc[nt] = __builtin_amdgcn_mfma_f32_32x32x16_bf16(a, bf, sc[nt], 0, 0, 0);
    }
  }

  // ---- softmax (per-row, rows complete in 32-lane groups) ----
  const float scale = 0.20412414523193154f;  // 1/sqrt(24)
  float rinv[16];
  #pragma unroll
  for (int r = 0; r < 16; ++r) {
    float mx = -1e30f;
    #pragma unroll
    for (int nt = 0; nt < 4; ++nt) {
      float s = sc[nt][r] * scale;
      // col = nt*32+m32; invalid keys >= 100 -> only nt==3, m32>=4
      if (nt == 3 && m32 >= 4) s = -1e30f;
      sc[nt][r] = s;
      mx = fmaxf(mx, s);
    }
    #pragma unroll
    for (int off = 1; off < 32; off <<= 1) mx = fmaxf(mx, __shfl_xor(mx, off));
    float sum = 0.f;
    #pragma unroll
    for (int nt = 0; nt < 4; ++nt) {
      float e = expf(sc[nt][r] - mx);   // masked entries underflow to 0
      sc[nt][r] = e;
      sum += e;
    }
    #pragma unroll
    for (int off = 1; off < 32; off <<= 1) sum += __shfl_xor(sum, off);
    rinv[r] = 1.f / sum;
  }
  // store P (bf16) — wave-private region
  #pragma unroll
  for (int r = 0; r < 16; ++r) {
    int rowl = (r & 3) + 8 * (r >> 2) + 4 * half;
    #pragma unroll
    for (int nt = 0; nt < 4; ++nt)
      Ps[(w * 32 + rowl) * 136 + nt * 32 + m32] = __float2bfloat16(sc[nt][r]);
  }
  __syncthreads();

  // ---- PV ----
  floatx16 ov;
  #pragma unroll
  for (int r = 0; r < 16; ++r) ov[r] = 0.f;
  #pragma unroll
  for (int kt = 0; kt < 8; ++kt) {
    int ko = kt * 16 + half * 8;
    short8 a = *(const short8*)&Ps[(w * 32 + m32) * 136 + ko];
    short8 bf = *(const short8*)&Vt[m32 * 136 + ko];
    ov = __builtin_amdgcn_mfma_f32_32x32x16_bf16(a, bf, ov, 0, 0, 0);
  }
  #pragma unroll
  for (int r = 0; r < 16; ++r) {
    int rowl = (r & 3) + 8 * (r >> 2) + 4 * half;
    int q = w * 32 + rowl;
    if (m32 < DH_ && q < S_)
      o[((size_t)(b * S_ + q)) * D_ + hh * DH_ + m32] =
          __float2bfloat16(ov[r] * rinv[r]);
  }
}

// ---------------------------------------------------------------------------
// out-proj + residual + LN. 128 threads = 2 waves, BM=64 -> 200 blocks.
// Wave owns 32 rows x all 6 n-tiles -> LN fully in 32-lane groups.
// ---------------------------------------------------------------------------
__global__ __launch_bounds__(128)
void outln_kernel(const __hip_bfloat16* __restrict__ A,
                  const __hip_bfloat16* __restrict__ Wt,
                  const float* __restrict__ bias,
                  const float* __restrict__ g, const float* __restrict__ bvec,
                  float* __restrict__ x, __hip_bfloat16* __restrict__ xb)
{
  __shared__ __align__(16) __hip_bfloat16 Asl[64 * 40];
  __shared__ __align__(16) __hip_bfloat16 Bsl[192 * 40];
  int tid = threadIdx.x, lane = tid & 63, w = tid >> 6;
  int m32 = lane & 31, half = lane >> 5;
  int bm = blockIdx.x * 64;

  floatx16 acc[6];
  #pragma unroll
  for (int nt = 0; nt < 6; ++nt)
    #pragma unroll
    for (int r = 0; r < 16; ++r) acc[nt][r] = 0.f;

  for (int k0 = 0; k0 < D_; k0 += 32) {
    {
      int r = tid >> 1, h = tid & 1;
      const float4* s = (const float4*)(A + (size_t)(bm + r) * D_ + k0 + h * 16);
      float4* d = (float4*)&Asl[r * 40 + h * 16];
      d[0] = s[0]; d[1] = s[1];
    }
    for (int e = tid; e < 384; e += 128) {
      int r = e >> 1, h = e & 1;
      const float4* s = (const float4*)(Wt + (size_t)r * D_ + k0 + h * 16);
      float4* d = (float4*)&Bsl[r * 40 + h * 16];
      d[0] = s[0]; d[1] = s[1];
    }
    __syncthreads();
    #pragma unroll
    for (int kc = 0; kc < 2; ++kc) {
      int ko = kc * 16 + half * 8;
      short8 a = *(const short8*)&Asl[(w * 32 + m32) * 40 + ko];
      #pragma unroll
      for (int nt = 0; nt < 6; ++nt) {
        short8 bf = *(const short8*)&Bsl[(nt * 32 + m32) * 40 + ko];
        acc[nt] = __builtin_amdgcn_mfma_f32_32x32x16_bf16(a, bf, acc[nt], 0, 0, 0);
      }
    }
    __syncthreads();
  }

  float cbias[6], cg[6], cb2[6];
  #pragma unroll
  for (int nt = 0; nt < 6; ++nt) {
    int col = nt * 32 + m32;
    cbias[nt] = bias[col]; cg[nt] = g[col]; cb2[nt] = bvec[col];
  }
  int rowbase = bm + w * 32 + 4 * half;
  #pragma unroll
  for (int r = 0; r < 16; ++r) {
    int row = rowbase + (r & 3) + 8 * (r >> 2);
    float part = 0.f;
    #pragma unroll
    for (int nt = 0; nt < 6; ++nt) {
      int col = nt * 32 + m32;
      float t = acc[nt][r] + cbias[nt] + x[(size_t)row * D_ + col];
      acc[nt][r] = t;
      part += t;
    }
    #pragma unroll
    for (int off = 1; off < 32; off <<= 1) part += __shfl_xor(part, off);
    float mean = part * (1.f / (float)D_);
    float sq = 0.f;
    #pragma unroll
    for (int nt = 0; nt < 6; ++nt) { float dd = acc[nt][r] - mean; sq += dd * dd; }
    #pragma unroll
    for (int off = 1; off < 32; off <<= 1) sq += __shfl_xor(sq, off);
    float inv = rsqrtf(sq * (1.f / (float)D_) + 1e-5f);
    #pragma unroll
    for (int nt = 0; nt < 6; ++nt) {
      int col = nt * 32 + m32;
      float ovv = (acc[nt][r] - mean) * inv * cg[nt] + cb2[nt];
      x[(size_t)row * D_ + col] = ovv;
      xb[(size_t)row * D_ + col] = __float2bfloat16(ovv);
    }
  }
}

// ---------------------------------------------------------------------------
// ff1 + ff2 + residual + LN (validated R4). 256 threads, BM=64 -> 200 blocks.
// ---------------------------------------------------------------------------
__global__ __launch_bounds__(256)
void ffln_kernel(const __hip_bfloat16* __restrict__ xbi,
                 const __hip_bfloat16* __restrict__ W1, const float* __restrict__ b1,
                 const __hip_bfloat16* __restrict__ W2, const float* __restrict__ b2,
                 const float* __restrict__ g, const float* __restrict__ bvec,
                 float* __restrict__ x, __hip_bfloat16* __restrict__ xb)
{
  __shared__ __align__(16) __hip_bfloat16 C1[64 * 260];
  __shared__ __align__(16) __hip_bfloat16 Asl[64 * 40];
  __shared__ __align__(16) __hip_bfloat16 Bsl[256 * 40];
  __shared__ float psum[64][2];
  __shared__ float psq[64][2];
  int tid = threadIdx.x, lane = tid & 63, w = tid >> 6;
  int m32 = lane & 31, half = lane >> 5;
  int mt = w & 1, ng = w >> 1;
  int bm = blockIdx.x * 64;

  floatx16 acc1[4];
  #pragma unroll
  for (int j = 0; j < 4; ++j)
    #pragma unroll
    for (int r = 0; r < 16; ++r) acc1[j][r] = 0.f;

  for (int k0 = 0; k0 < D_; k0 += 32) {
    if (tid < 128) {
      int r = tid >> 1, h = tid & 1;
      const float4* s = (const float4*)(xbi + (size_t)(bm + r) * D_ + k0 + h * 16);
      float4* d = (float4*)&Asl[r * 40 + h * 16];
      d[0] = s[0]; d[1] = s[1];
    }
    for (int e = tid; e < 512; e += 256) {
      int r = e >> 1, h = e & 1;
      const float4* s = (const float4*)(W1 + (size_t)r * D_ + k0 + h * 16);
      float4* d = (float4*)&Bsl[r * 40 + h * 16];
      d[0] = s[0]; d[1] = s[1];
    }
    __syncthreads();
    #pragma unroll
    for (int kc = 0; kc < 2; ++kc) {
      int ko = kc * 16 + half * 8;
      short8 a = *(const short8*)&Asl[(mt * 32 + m32) * 40 + ko];
      #pragma unroll
      for (int j = 0; j < 4; ++j) {
        short8 bf = *(const short8*)&Bsl[((ng * 4 + j) * 32 + m32) * 40 + ko];
        acc1[j] = __builtin_amdgcn_mfma_f32_32x32x16_bf16(a, bf, acc1[j], 0, 0, 0);
      }
    }
    __syncthreads();
  }
  {
    int rowb = mt * 32 + 4 * half;
    #pragma unroll
    for (int j = 0; j < 4; ++j) {
      int col = (ng * 4 + j) * 32 + m32;
      float cb = b1[col];
      #pragma unroll
      for (int r = 0; r < 16; ++r) {
        int row = rowb + (r & 3) + 8 * (r >> 2);
        C1[row * 260 + col] = __float2bfloat16(fmaxf(acc1[j][r] + cb, 0.f));
      }
    }
  }
  __syncthreads();

  floatx16 acc2[3];
  #pragma unroll
  for (int j = 0; j < 3; ++j)
    #pragma unroll
    for (int r = 0; r < 16; ++r) acc2[j][r] = 0.f;

  for (int k0 = 0; k0 < DFF_; k0 += 32) {
    for (int e = tid; e < 384; e += 256) {
      int r = e >> 1, h = e & 1;
      const float4* s = (const float4*)(W2 + (size_t)r * DFF_ + k0 + h * 16);
      float4* d = (float4*)&Bsl[r * 40 + h * 16];
      d[0] = s[0]; d[1] = s[1];
    }
    __syncthreads();
    #pragma unroll
    for (int kc = 0; kc < 2; ++kc) {
      int ko = kc * 16 + half * 8;
      short8 a = ld_frag8(&C1[(mt * 32 + m32) * 260 + k0 + ko]);
      #pragma unroll
      for (int j = 0; j < 3; ++j) {
        short8 bf = *(const short8*)&Bsl[((ng * 3 + j) * 32 + m32) * 40 + ko];
        acc2[j] = __builtin_amdgcn_mfma_f32_32x32x16_bf16(a, bf, acc2[j], 0, 0, 0);
      }
    }
    __syncthreads();
  }

  int rowb = mt * 32 + 4 * half;
  #pragma unroll
  for (int r = 0; r < 16; ++r) {
    int rl = rowb + (r & 3) + 8 * (r >> 2);
    int row = bm + rl;
    float p = 0.f;
    #pragma unroll
    for (int j = 0; j < 3; ++j) {
      int col = (ng * 3 + j) * 32 + m32;
      float t = acc2[j][r] + b2[col] + x[(size_t)row * D_ + col];
      acc2[j][r] = t;
      p += t;
    }
    #pragma unroll
    for (int off = 1; off < 32; off <<= 1) p += __shfl_xor(p, off);
    if (m32 == 0) psum[rl][ng] = p;
  }
  __syncthreads();
  float mean[16];
  #pragma unroll
  for (int r = 0; r < 16; ++r) {
    int rl = rowb + (r & 3) + 8 * (r >> 2);
    mean[r] = (psum[rl][0] + psum[rl][1]) * (1.f / (float)D_);
  }
  #pragma unroll
  for (int r = 0; r < 16; ++r) {
    int rl = rowb + (r & 3) + 8 * (r >> 2);
    float s = 0.f;
    #pragma unroll
    for (int j = 0; j < 3; ++j) { float dd = acc2[j][r] - mean[r]; s += dd * dd; }
    #pragma unroll
    for (int off = 1; off < 32; off <<= 1) s += __shfl_xor(s, off);
    if (m32 == 0) psq[rl][ng] = s;
  }
  __syncthreads();
  #pragma unroll
  for (int r = 0; r < 16; ++r) {
    int rl = rowb + (r & 3) + 8 * (r >> 2);
    int row = bm + rl;
    float inv = rsqrtf((psq[rl][0] + psq[rl][1]) * (1.f / (float)D_) + 1e-5f);
    #pragma unroll
    for (int j = 0; j < 3; ++j) {
      int col = (ng * 3 + j) * 32 + m32;
      float ovv = (acc2[j][r] - mean[r]) * inv * g[col] + bvec[col];
      x[(size_t)row * D_ + col] = ovv;
      xb[(size_t)row * D_ + col] = __float2bfloat16(ovv);
    }
  }
}

// ---------------------------------------------------------------------------
// Encoder phase (a): gathers + spatial MLP -> global wcomb bf16 (256000x128).
// 32 (bs,w) rows per block, grid 8000 -> massive TLP.
// ---------------------------------------------------------------------------
__global__ __launch_bounds__(256)
void wcomb_kernel(const int* __restrict__ title_idx, const int* __restrict__ class_idx,
                  const int* __restrict__ process_idx,
                  const float* __restrict__ rect, const float* __restrict__ flags,
                  const float* __restrict__ te, const float* __restrict__ ce,
                  const float* __restrict__ pe,
                  const float* __restrict__ sw1, const float* __restrict__ sb1,
                  const float* __restrict__ sw2, const float* __restrict__ sb2,
                  __hip_bfloat16* __restrict__ wc)
{
  __shared__ float hidS[16 * 68];
  int tid = threadIdx.x, tx = tid & 15, ty = tid >> 4;
  int r0 = blockIdx.x * 32;

  for (int idx = tid; idx < 32 * 96; idx += 256) {
    int r = idx / 96, c = idx - r * 96;
    int rg = r0 + r;
    float v;
    if (c < 32)      v = te[title_idx[rg] * 32 + c];
    else if (c < 64) v = ce[class_idx[rg] * 32 + (c - 32)];
    else             v = pe[process_idx[rg] * 32 + (c - 64)];
    wc[(size_t)rg * 128 + c] = __float2bfloat16(v);
  }

  for (int chunk = 0; chunk < 2; ++chunk) {
    int r = chunk * 16 + ty;
    int rg = r0 + r;
    float4 rc = *(const float4*)(rect + (size_t)rg * 4);
    float f0 = flags[rg * 2], f1 = flags[rg * 2 + 1];
    __syncthreads();
    #pragma unroll
    for (int u = 0; u < 4; ++u) {
      int cc = tx + 16 * u;
      const float* w1 = sw1 + cc * 6;
      float a = sb1[cc] + w1[0]*rc.x + w1[1]*rc.y + w1[2]*rc.z + w1[3]*rc.w
                        + w1[4]*f0 + w1[5]*f1;
      hidS[ty * 68 + cc] = fmaxf(a, 0.f);
    }
    __syncthreads();
    #pragma unroll
    for (int v2 = 0; v2 < 2; ++v2) {
      int cc = tx + 16 * v2;
      const float4* w2 = (const float4*)(sw2 + cc * 64);
      const float4* hp = (const float4*)&hidS[ty * 68];
      float a = sb2[cc];
      #pragma unroll
      for (int k4 = 0; k4 < 16; ++k4) {
        float4 ww = w2[k4], h = hp[k4];
        a += ww.x*h.x + ww.y*h.y + ww.z*h.z + ww.w*h.w;
      }
      wc[(size_t)rg * 128 + 96 + cc] = __float2bfloat16(a);
    }
  }
}

// ---------------------------------------------------------------------------
// Encoder phase (b): wfuse MFMA GEMM from global wcomb + masked-avg epilogue
// + posenc + activity fusion. 8 bs (160 rows) per block, grid 1600, ~30KB LDS.
// ---------------------------------------------------------------------------
__global__ __launch_bounds__(256)
void wfuse_avg_kernel(const __hip_bfloat16* __restrict__ wc,
                      const __hip_bfloat16* __restrict__ wfwb, const float* __restrict__ wfb,
                      const float* __restrict__ window_mask,
                      const int* __restrict__ activity_type,
                      const float* __restrict__ mouse_pos,
                      const float* __restrict__ keyboard_active,
                      const float* __restrict__ mw1, const float* __restrict__ mb1,
                      const float* __restrict__ mw2, const float* __restrict__ mb2,
                      const float* __restrict__ act_emb, const float* __restrict__ kbw,
                      const float* __restrict__ kbb,
                      const float* __restrict__ afw, const float* __restrict__ afb,
                      float* __restrict__ x, __hip_bfloat16* __restrict__ xb)
{
  __shared__ __align__(16) __hip_bfloat16 Asl[160 * 40];
  __shared__ __align__(16) __hip_bfloat16 Bsl[128 * 40];
  __shared__ float avgS[8 * 132];
  __shared__ float scratch[544];
  __shared__ float maskS[160];

  int tid = threadIdx.x;
  int bs0 = blockIdx.x * 8;
  int row0 = bs0 * W_;
  int lane = tid & 63, w = tid >> 6;
  int m32 = lane & 31, half = lane >> 5;

  for (int e = tid; e < 160; e += 256) maskS[e] = window_mask[row0 + e];
  for (int e = tid; e < 8 * 132; e += 256) avgS[e] = 0.f;

  floatx16 acc[5];
  #pragma unroll
  for (int mt = 0; mt < 5; ++mt)
    #pragma unroll
    for (int r = 0; r < 16; ++r) acc[mt][r] = 0.f;

  for (int kt = 0; kt < 4; ++kt) {
    int k0 = kt * 32;
    for (int e = tid; e < 640; e += 256) {
      int r = e >> 2, seg = e & 3;
      *(float4*)&Asl[r * 40 + seg * 8] =
          *(const float4*)&wc[(size_t)(row0 + r) * 128 + k0 + seg * 8];
    }
    {
      int r = tid >> 1, h = tid & 1;
      const float4* s = (const float4*)(wfwb + (size_t)r * 128 + k0 + h * 16);
      float4* d = (float4*)&Bsl[r * 40 + h * 16];
      d[0] = s[0]; d[1] = s[1];
    }
    __syncthreads();
    #pragma unroll
    for (int kc = 0; kc < 2; ++kc) {
      int ko = kc * 16 + half * 8;
      short8 bf = *(const short8*)&Bsl[(w * 32 + m32) * 40 + ko];
      #pragma unroll
      for (int mt = 0; mt < 5; ++mt) {
        short8 a = *(const short8*)&Asl[(mt * 32 + m32) * 40 + ko];
        acc[mt] = __builtin_amdgcn_mfma_f32_32x32x16_bf16(a, bf, acc[mt], 0, 0, 0);
      }
    }
    __syncthreads();
  }
  {
    int col = w * 32 + m32;
    float cb = wfb[col];
    #pragma unroll
    for (int mt = 0; mt < 5; ++mt) {
      int rowb = mt * 32 + 4 * half;
      #pragma unroll
      for (int r = 0; r < 16; ++r) {
        int row = rowb + (r & 3) + 8 * (r >> 2);
        float val = fmaxf(acc[mt][r] + cb, 0.f) * maskS[row];
        atomicAdd(&avgS[(row / 20) * 132 + col], val);
      }
    }
  }
  __syncthreads();

  for (int e = tid; e < 8 * 128; e += 256) {
    int bsl = e >> 7, col = e & 127;
    int bsg = bs0 + bsl;
    float v = avgS[bsl * 132 + col] * (1.f / (float)W_) + posenc(bsg % S_, col);
    x[(size_t)bsg * D_ + col] = v;
    xb[(size_t)bsg * D_ + col] = __float2bfloat16(v);
  }

  float* afA = scratch;
  float* afB = scratch + 4 * 68;
  for (int pass = 0; pass < 2; ++pass) {
    int bl = tid >> 6, ln = tid & 63;
    int bsg = bs0 + pass * 4 + bl;
    __syncthreads();
    if (ln < 32) {
      float mx = mouse_pos[bsg * 2 + 0] * (1.f / 1920.f);
      float my = mouse_pos[bsg * 2 + 1] * (1.f / 1080.f);
      afA[bl * 68 + ln] = fmaxf(mw1[ln * 2] * mx + mw1[ln * 2 + 1] * my + mb1[ln], 0.f);
    }
    __syncthreads();
    float cv;
    if (ln < 32) {
      float a = mb2[ln];
      #pragma unroll 8
      for (int k = 0; k < 32; ++k) a += mw2[ln * 32 + k] * afA[bl * 68 + k];
      cv = a;
    } else if (ln < 48) {
      cv = act_emb[activity_type[bsg] * 16 + (ln - 32)];
    } else {
      cv = kbw[ln - 48] * keyboard_active[bsg] + kbb[ln - 48];
    }
    __syncthreads();
    afB[bl * 68 + ln] = cv;
    __syncthreads();
    {
      float a = afb[ln];
      const float4* w4 = (const float4*)(afw + ln * 64);
      const float4* cp = (const float4*)&afB[bl * 68];
      #pragma unroll
      for (int k4 = 0; k4 < 16; ++k4) {
        float4 ww = w4[k4], c = cp[k4];
        a += ww.x*c.x + ww.y*c.y + ww.z*c.z + ww.w*c.w;
      }
      float v = fmaxf(a, 0.f);
      int cg = 128 + ln;
      float ovv = v + posenc(bsg % S_, cg);
      x[(size_t)bsg * D_ + cg] = ovv;
      xb[(size_t)bsg * D_ + cg] = __float2bfloat16(ovv);
    }
  }
}

// ---------------------------------------------------------------------------
// Fallback monolithic encoder (validated R4) — used if ws too small for wcomb.
// ---------------------------------------------------------------------------
__global__ __launch_bounds__(256)
void encode_mfma_kernel(
    const int* __restrict__ title_idx, const int* __restrict__ class_idx,
    const int* __restrict__ process_idx, const int* __restrict__ activity_type,
    const float* __restrict__ mouse_pos, const float* __restrict__ rect,
    const float* __restrict__ flags, const float* __restrict__ keyboard_active,
    const float* __restrict__ window_mask,
    const float* __restrict__ title_emb, const float* __restrict__ class_emb,
    const float* __restrict__ process_emb,
    const float* __restrict__ sw1, const float* __restrict__ sb1,
    const float* __restrict__ sw2, const float* __restrict__ sb2,
    const __hip_bfloat16* __restrict__ wfwb, const float* __restrict__ wfb,
    const float* __restrict__ mw1, const float* __restrict__ mb1,
    const float* __restrict__ mw2, const float* __restrict__ mb2,
    const float* __restrict__ act_emb, const float* __restrict__ kbw,
    const float* __restrict__ kbb,
    const float* __restrict__ afw, const float* __restrict__ afb,
    float* __restrict__ x, __hip_bfloat16* __restrict__ xb)
{
  __shared__ __align__(16) __hip_bfloat16 Awc[160 * 132];
  __shared__ __align__(16) __hip_bfloat16 Bsl[128 * 40];
  __shared__ float avgS[8 * 132];
  __shared__ float scratch[1088];
  __shared__ float maskS[160];

  int tid = threadIdx.x;
  int tx = tid & 15, ty = tid >> 4;
  int bs0 = blockIdx.x * 8;
  int row0 = bs0 * W_;

  for (int e = tid; e < 160; e += 256) maskS[e] = window_mask[row0 + e];
  for (int e = tid; e < 8 * 132; e += 256) avgS[e] = 0.f;

  for (int idx = tid; idx < 160 * 96; idx += 256) {
    int r = idx / 96, c = idx - r * 96;
    int rg = row0 + r;
    float v;
    if (c < 32)      v = title_emb[title_idx[rg] * 32 + c];
    else if (c < 64) v = class_emb[class_idx[rg] * 32 + (c - 32)];
    else             v = process_emb[process_idx[rg] * 32 + (c - 64)];
    Awc[r * 132 + c] = __float2bfloat16(v);
  }

  float* hidS = scratch;
  for (int chunk = 0; chunk < 10; ++chunk) {
    int r = chunk * 16 + ty;
    int rg = row0 + r;
    float4 rc = *(const float4*)(rect + (size_t)rg * 4);
    float f0 = flags[rg * 2], f1 = flags[rg * 2 + 1];
    __syncthreads();
    #pragma unroll
    for (int u = 0; u < 4; ++u) {
      int cc = tx + 16 * u;
      const float* w1 = sw1 + cc * 6;
      float a = sb1[cc] + w1[0]*rc.x + w1[1]*rc.y + w1[2]*rc.z + w1[3]*rc.w
                        + w1[4]*f0 + w1[5]*f1;
      hidS[ty * 68 + cc] = fmaxf(a, 0.f);
    }
    __syncthreads();
    #pragma unroll
    for (int v2 = 0; v2 < 2; ++v2) {
      int cc = tx + 16 * v2;
      const float4* w2 = (const float4*)(sw2 + cc * 64);
      const float4* hp = (const float4*)&hidS[ty * 68];
      float a = sb2[cc];
      #pragma unroll
      for (int k4 = 0; k4 < 16; ++k4) {
        float4 ww = w2[k4], h = hp[k4];
        a += ww.x*h.x + ww.y*h.y + ww.z*h.z + ww.w*h.w;
      }
      Awc[r * 132 + 96 + cc] = __float2bfloat16(a);
    }
  }
  __syncthreads();

  int lane = tid & 63, w = tid >> 6;
  int m32 = lane & 31, half = lane >> 5;
  floatx16 acc[5];
  #pragma unroll
  for (int mt = 0; mt < 5; ++mt)
    #pragma unroll
    for (int r = 0; r < 16; ++r) acc[mt][r] = 0.f;

  for (int kt = 0; kt < 4; ++kt) {
    int k0 = kt * 32;
    {
      int r = tid >> 1, h = tid & 1;
      const float4* s = (const float4*)(wfwb + (size_t)r * 128 + k0 + h * 16);
      float4* d = (float4*)&Bsl[r * 40 + h * 16];
      d[0] = s[0]; d[1] = s[1];
    }
    __syncthreads();
    #pragma unroll
    for (int kc = 0; kc < 2; ++kc) {
      int ko = kc * 16 + half * 8;
      short8 bf = *(const short8*)&Bsl[(w * 32 + m32) * 40 + ko];
      #pragma unroll
      for (int mt = 0; mt < 5; ++mt) {
        short8 a = ld_frag8(&Awc[(mt * 32 + m32) * 132 + k0 + ko]);
        acc[mt] = __builtin_amdgcn_mfma_f32_32x32x16_bf16(a, bf, acc[mt], 0, 0, 0);
      }
    }
    __syncthreads();
  }
  {
    int col = w * 32 + m32;
    float cb = wfb[col];
    #pragma unroll
    for (int mt = 0; mt < 5; ++mt) {
      int rowb = mt * 32 + 4 * half;
      #pragma unroll
      for (int r = 0; r < 16; ++r) {
        int row = rowb + (r & 3) + 8 * (r >> 2);
        float val = fmaxf(acc[mt][r] + cb, 0.f) * maskS[row];
        atomicAdd(&avgS[(row / 20) * 132 + col], val);
      }
    }
  }
  __syncthreads();

  for (int e = tid; e < 8 * 128; e += 256) {
    int bsl = e >> 7, col = e & 127;
    int bsg = bs0 + bsl;
    float v = avgS[bsl * 132 + col] * (1.f / (float)W_) + posenc(bsg % S_, col);
    x[(size_t)bsg * D_ + col] = v;
    xb[(size_t)bsg * D_ + col] = __float2bfloat16(v);
  }

  float* afA = scratch;
  float* afB = scratch + 4 * 68;
  for (int pass = 0; pass < 2; ++pass) {
    int bl = tid >> 6, ln = tid & 63;
    int bsg = bs0 + pass * 4 + bl;
    __syncthreads();
    if (ln < 32) {
      float mx = mouse_pos[bsg * 2 + 0] * (1.f / 1920.f);
      float my = mouse_pos[bsg * 2 + 1] * (1.f / 1080.f);
      afA[bl * 68 + ln] = fmaxf(mw1[ln * 2] * mx + mw1[ln * 2 + 1] * my + mb1[ln], 0.f);
    }
    __syncthreads();
    float cv;
    if (ln < 32) {
      float a = mb2[ln];
      #pragma unroll 8
      for (int k = 0; k < 32; ++k) a += mw2[ln * 32 + k] * afA[bl * 68 + k];
      cv = a;
    } else if (ln < 48) {
      cv = act_emb[activity_type[bsg] * 16 + (ln - 32)];
    } else {
      cv = kbw[ln - 48] * keyboard_active[bsg] + kbb[ln - 48];
    }
    __syncthreads();
    afB[bl * 68 + ln] = cv;
    __syncthreads();
    {
      float a = afb[ln];
      const float4* w4 = (const float4*)(afw + ln * 64);
      const float4* cp = (const float4*)&afB[bl * 68];
      #pragma unroll
      for (int k4 = 0; k4 < 16; ++k4) {
        float4 ww = w4[k4], c = cp[k4];
        a += ww.x*c.x + ww.y*c.y + ww.z*c.z + ww.w*c.w;
      }
      float v = fmaxf(a, 0.f);
      int cg = 128 + ln;
      float ovv = v + posenc(bsg % S_, cg);
      x[(size_t)bsg * D_ + cg] = ovv;
      xb[(size_t)bsg * D_ + cg] = __float2bfloat16(ovv);
    }
  }
}

// ---------------------------------------------------------------------------
// Head (fp32): one block per (w,b) slot.
// ---------------------------------------------------------------------------
__global__ __launch_bounds__(256)
void head_kernel(const float* __restrict__ x, const float* __restrict__ noise,
                 const float* __restrict__ pw1, const float* __restrict__ pb1,
                 const float* __restrict__ pw2, const float* __restrict__ pb2,
                 const float* __restrict__ ew1, const float* __restrict__ eb1,
                 const float* __restrict__ ew2, const float* __restrict__ eb2,
                 float* __restrict__ out)
{
  int idx = blockIdx.x;
  int b = idx & 127, w = idx >> 7;
  int tid = threadIdx.x;
  __shared__ float slot[192];
  __shared__ float ph[256];
  __shared__ float eh[128];
  if (tid < 192)
    slot[tid] = x[((size_t)b * S_ + (S_ - 1)) * D_ + tid]
              + noise[((size_t)w * B_ + b) * D_ + tid] * 0.1f;
  __syncthreads();
  {
    const float4* wr = (const float4*)(pw1 + (size_t)tid * D_);
    const float4* sp = (const float4*)slot;
    float a = pb1[tid];
    #pragma unroll 12
    for (int k = 0; k < 48; ++k) {
      float4 wv = wr[k], sv = sp[k];
      a += wv.x*sv.x + wv.y*sv.y + wv.z*sv.z + wv.w*sv.w;
    }
    ph[tid] = fmaxf(a, 0.f);
  }
  if (tid < 128) {
    const float4* wr = (const float4*)(ew1 + (size_t)tid * D_);
    const float4* sp = (const float4*)slot;
    float a = eb1[tid];
    #pragma unroll 12
    for (int k = 0; k < 48; ++k) {
      float4 wv = wr[k], sv = sp[k];
      a += wv.x*sv.x + wv.y*sv.y + wv.z*sv.z + wv.w*sv.w;
    }
    eh[tid] = fmaxf(a, 0.f);
  }
  __syncthreads();
  if (tid < 4) {
    float a = pb2[tid];
    const float4* wr = (const float4*)(pw2 + tid * 256);
    const float4* pp = (const float4*)ph;
    for (int k = 0; k < 64; ++k) {
      float4 wv = wr[k], pv = pp[k];
      a += wv.x*pv.x + wv.y*pv.y + wv.z*pv.z + wv.w*pv.w;
    }
    out[((size_t)b * W_ + w) * 4 + tid] = a;
  }
  if (tid == 4) {
    float a = eb2[0];
    const float4* wr = (const float4*)ew2;
    const float4* pp = (const float4*)eh;
    for (int k = 0; k < 32; ++k) {
      float4 wv = wr[k], pv = pp[k];
      a += wv.x*pv.x + wv.y*pv.y + wv.z*pv.z + wv.w*pv.w;
    }
    out[(size_t)B_ * W_ * 4 + (size_t)b * W_ + w] = 1.f / (1.f + expf(-a));
  }
}

// ---------------------------------------------------------------------------
extern "C" void kernel_launch(void* const* d_in, const int* in_sizes, int n_in,
                              void* d_out, int out_size, void* d_ws, size_t ws_size,
                              hipStream_t stream)
{
  const int*   title_idx       = (const int*)  d_in[0];
  const int*   class_idx       = (const int*)  d_in[1];
  const int*   process_idx     = (const int*)  d_in[2];
  const int*   activity_type   = (const int*)  d_in[3];
  const float* mouse_pos       = (const float*)d_in[4];
  const float* rect            = (const float*)d_in[5];
  const float* flags           = (const float*)d_in[6];
  const float* keyboard_active = (const float*)d_in[7];
  const float* window_mask     = (const float*)d_in[8];
  const float* noise           = (const float*)d_in[9];
  const float* title_emb       = (const float*)d_in[10];
  const float* class_emb       = (const float*)d_in[11];
  const float* process_emb     = (const float*)d_in[12];
  const float* spatial_w1      = (const float*)d_in[13];
  const float* spatial_b1      = (const float*)d_in[14];
  const float* spatial_w2      = (const float*)d_in[15];
  const float* spatial_b2      = (const float*)d_in[16];
  const float* wfuse_w         = (const float*)d_in[17];
  const float* wfuse_b         = (const float*)d_in[18];
  const float* mouse_w1        = (const float*)d_in[19];
  const float* mouse_b1        = (const float*)d_in[20];
  const float* mouse_w2        = (const float*)d_in[21];
  const float* mouse_b2        = (const float*)d_in[22];
  const float* act_emb         = (const float*)d_in[23];
  const float* kbd_w           = (const float*)d_in[24];
  const float* kbd_b           = (const float*)d_in[25];
  const float* afuse_w         = (const float*)d_in[26];
  const float* afuse_b         = (const float*)d_in[27];
  const float* qkv_w           = (const float*)d_in[28];
  const float* qkv_b           = (const float*)d_in[29];
  const float* out_w           = (const float*)d_in[30];
  const float* out_b           = (const float*)d_in[31];
  const float* ff1_w           = (const float*)d_in[32];
  const float* ff1_b           = (const float*)d_in[33];
  const float* ff2_w           = (const float*)d_in[34];
  const float* ff2_b           = (const float*)d_in[35];
  const float* ln1_g           = (const float*)d_in[36];
  const float* ln1_b           = (const float*)d_in[37];
  const float* ln2_g           = (const float*)d_in[38];
  const float* ln2_b           = (const float*)d_in[39];
  const float* proj_w1         = (const float*)d_in[40];
  const float* proj_b1         = (const float*)d_in[41];
  const float* proj_w2         = (const float*)d_in[42];
  const float* proj_b2         = (const float*)d_in[43];
  const float* ex_w1           = (const float*)d_in[44];
  const float* ex_b1           = (const float*)d_in[45];
  const float* ex_w2           = (const float*)d_in[46];
  const float* ex_b2           = (const float*)d_in[47];

  float* out = (float*)d_out;

  // workspace layout
  float* x = (float*)d_ws;                                      // BS*192 f32
  __hip_bfloat16* xb   = (__hip_bfloat16*)(x + (size_t)BS_ * D_);
  __hip_bfloat16* qkvb = xb   + (size_t)BS_ * D_;
  __hip_bfloat16* attb = qkvb + (size_t)BS_ * THREED_;
  __hip_bfloat16* wqb  = attb + (size_t)BS_ * D_;
  __hip_bfloat16* wob  = wqb  + (size_t)L_ * THREED_ * D_;
  __hip_bfloat16* wf1b = wob  + (size_t)L_ * D_ * D_;
  __hip_bfloat16* wf2b = wf1b + (size_t)L_ * DFF_ * D_;
  __hip_bfloat16* wfwb = wf2b + (size_t)L_ * D_ * DFF_;
  __hip_bfloat16* wcG  = wfwb + (size_t)128 * 128;              // 256000*128 bf16
  size_t need = ((char*)(wcG + (size_t)BS_ * W_ * 128)) - (char*)d_ws;
  bool split_enc = (ws_size >= need);
  (void)n_in; (void)in_sizes; (void)out_size;

  convert5_kernel<<<728, 256, 0, stream>>>(qkv_w, wqb, out_w, wob,
                                           ff1_w, wf1b, ff2_w, wf2b,
                                           wfuse_w, wfwb);

  if (split_enc) {
    wcomb_kernel<<<(BS_ * W_) / 32, 256, 0, stream>>>(
        title_idx, class_idx, process_idx, rect, flags,
        title_emb, class_emb, process_emb,
        spatial_w1, spatial_b1, spatial_w2, spatial_b2, wcG);
    wfuse_avg_kernel<<<BS_ / 8, 256, 0, stream>>>(
        wcG, wfwb, wfuse_b, window_mask, activity_type, mouse_pos,
        keyboard_active, mouse_w1, mouse_b1, mouse_w2, mouse_b2,
        act_emb, kbd_w, kbd_b, afuse_w, afuse_b, x, xb);
  } else {
    encode_mfma_kernel<<<BS_ / 8, 256, 0, stream>>>(
        title_idx, class_idx, process_idx, activity_type, mouse_pos, rect, flags,
        keyboard_active, window_mask, title_emb, class_emb, process_emb,
        spatial_w1, spatial_b1, spatial_w2, spatial_b2, wfwb, wfuse_b,
        mouse_w1, mouse_b1, mouse_w2, mouse_b2, act_emb, kbd_w, kbd_b,
        afuse_w, afuse_b, x, xb);
  }

  for (int l = 0; l < L_; ++l) {
    qkv_gemm_kernel<<<dim3(THREED_ / 64, BS_ / 128), 128, 0, stream>>>(
        xb, wqb + (size_t)l * THREED_ * D_, qkv_b + (size_t)l * THREED_, qkvb);
    attn_mfma_kernel<<<B_ * H_, 256, 0, stream>>>(qkvb, attb);
    outln_kernel<<<BS_ / 64, 128, 0, stream>>>(
        attb, wob + (size_t)l * D_ * D_, out_b + (size_t)l * D_,
        ln1_g + (size_t)l * D_, ln1_b + (size_t)l * D_, x, xb);
    ffln_kernel<<<BS_ / 64, 256, 0, stream>>>(
        xb, wf1b + (size_t)l * DFF_ * D_, ff1_b + (size_t)l * DFF_,
        wf2b + (size_t)l * D_ * DFF_, ff2_b + (size_t)l * D_,
        ln2_g + (size_t)l * D_, ln2_b + (size_t)l * D_, x, xb);
  }

  head_kernel<<<W_ * B_, 256, 0, stream>>>(
      x, noise, proj_w1, proj_b1, proj_w2, proj_b2,
      ex_w1, ex_b1, ex_w2, ex_b2, out);
}

// Round 8
// 1017.542 us; speedup vs baseline: 1.6099x; 1.3546x over previous
//
#include <hip/hip_runtime.h>
#include <hip/hip_bf16.h>
#include <math.h>

#define B_ 128
#define S_ 100
#define W_ 20
#define D_ 192
#define L_ 6
#define H_ 8
#define DFF_ 256
#define DH_ 24
#define BS_ (B_*S_)
#define THREED_ 576

typedef short short8 __attribute__((ext_vector_type(8)));
typedef float floatx16 __attribute__((ext_vector_type(16)));

__device__ __forceinline__ float posenc(int s, int c) {
  float freq = expf(-logf(10000.f) * (float)(2 * (c >> 1)) / (float)D_);
  float ang = (float)s * freq;
  return (c & 1) ? cosf(ang) : sinf(ang);
}

// ---------------------------------------------------------------------------
// fp32->bf16 weight conversion (2048 elems/block). qkv 324 | out 108 |
// ff1 144 | ff2 144 blocks. Grid = 720.
// ---------------------------------------------------------------------------
__global__ __launch_bounds__(256)
void convert4_kernel(const float* __restrict__ s0, __hip_bfloat16* __restrict__ d0,
                     const float* __restrict__ s1, __hip_bfloat16* __restrict__ d1,
                     const float* __restrict__ s2, __hip_bfloat16* __restrict__ d2,
                     const float* __restrict__ s3, __hip_bfloat16* __restrict__ d3)
{
  int b = blockIdx.x;
  const float* s; __hip_bfloat16* d; int base;
  if      (b < 324) { s = s0; d = d0; base = b; }
  else if (b < 432) { s = s1; d = d1; base = b - 324; }
  else if (b < 576) { s = s2; d = d2; base = b - 432; }
  else              { s = s3; d = d3; base = b - 576; }
  int i = (base * 256 + threadIdx.x) * 8;
  float4 v0 = *(const float4*)(s + i);
  float4 v1 = *(const float4*)(s + i + 4);
  __hip_bfloat162* d2p = (__hip_bfloat162*)(d + i);
  d2p[0] = __float22bfloat162_rn(make_float2(v0.x, v0.y));
  d2p[1] = __float22bfloat162_rn(make_float2(v0.z, v0.w));
  d2p[2] = __float22bfloat162_rn(make_float2(v1.x, v1.y));
  d2p[3] = __float22bfloat162_rn(make_float2(v1.z, v1.w));
}

// ---------------------------------------------------------------------------
// Encoder precompute (algebraic fold of wfuse):
//   TE2[v][o] = sum_k te[v][k]  * wfw[o][k]        (1000x128)
//   CE2[v][o] = sum_k ce[v][k]  * wfw[o][32+k]     (500x128)
//   PE2[v][o] = sum_k pe[v][k]  * wfw[o][64+k]     (1000x128)
//   WSPt[j][o] = sum_k wfw[o][96+k] * sw2[k][j]    (64x128, transposed)
//   wfb2[o]   = wfb[o] + sum_k wfw[o][96+k] * sb2[k]
// Grid = 1250 + 32 + 1 = 1283 blocks.
// ---------------------------------------------------------------------------
__global__ __launch_bounds__(256)
void prep_kernel(const float* __restrict__ te, const float* __restrict__ ce,
                 const float* __restrict__ pe, const float* __restrict__ wfw,
                 const float* __restrict__ wfb, const float* __restrict__ sw2,
                 const float* __restrict__ sb2,
                 float* __restrict__ TE2, float* __restrict__ CE2,
                 float* __restrict__ PE2, float* __restrict__ WSPt,
                 float* __restrict__ wfb2)
{
  int blk = blockIdx.x, tid = threadIdx.x;
  if (blk < 1250) {
    int item = blk * 256 + tid;          // < 320000
    int v = item >> 7, o = item & 127;
    const float* src; float* dst; int base, vv;
    if (v < 1000)      { src = te; dst = TE2; base = 0;  vv = v; }
    else if (v < 1500) { src = ce; dst = CE2; base = 32; vv = v - 1000; }
    else               { src = pe; dst = PE2; base = 64; vv = v - 1500; }
    float a = 0.f;
    #pragma unroll 8
    for (int k = 0; k < 32; ++k) a += src[vv * 32 + k] * wfw[o * 128 + base + k];
    dst[vv * 128 + o] = a;
  } else if (blk < 1282) {
    int item = (blk - 1250) * 256 + tid; // < 8192
    int j = item >> 7, o = item & 127;
    float a = 0.f;
    #pragma unroll 8
    for (int k = 0; k < 32; ++k) a += wfw[o * 128 + 96 + k] * sw2[k * 64 + j];
    WSPt[j * 128 + o] = a;
  } else if (tid < 128) {
    float a = wfb[tid];
    #pragma unroll 8
    for (int k = 0; k < 32; ++k) a += wfw[tid * 128 + 96 + k] * sb2[k];
    wfb2[tid] = a;
  }
}

// ---------------------------------------------------------------------------
// Encoder: 2 bs per block, 256 threads (2 groups x 128 cols). Per window w:
// h1 = relu(6->64 MLP); col c: val = TE2[t][c]+CE2[ci][c]+PE2[p][c]+wfb2[c]
//      + sum_j h1[j]*WSP[j][c]; acc += relu(val)*mask. Then avg+posenc,
// then activity fusion for cols 128..191. LDS ~35 KB -> 4 blocks/CU.
// ---------------------------------------------------------------------------
__global__ __launch_bounds__(256)
void encode2_kernel(
    const int* __restrict__ title_idx, const int* __restrict__ class_idx,
    const int* __restrict__ process_idx, const int* __restrict__ activity_type,
    const float* __restrict__ mouse_pos, const float* __restrict__ rect,
    const float* __restrict__ flags, const float* __restrict__ keyboard_active,
    const float* __restrict__ window_mask,
    const float* __restrict__ sw1, const float* __restrict__ sb1,
    const float* __restrict__ TE2, const float* __restrict__ CE2,
    const float* __restrict__ PE2, const float* __restrict__ WSPt,
    const float* __restrict__ wfb2,
    const float* __restrict__ mw1, const float* __restrict__ mb1,
    const float* __restrict__ mw2, const float* __restrict__ mb2,
    const float* __restrict__ act_emb, const float* __restrict__ kbw,
    const float* __restrict__ kbb,
    const float* __restrict__ afw, const float* __restrict__ afb,
    float* __restrict__ x, __hip_bfloat16* __restrict__ xb)
{
  __shared__ float WSPl[64 * 128];   // 32768 B, [j][c]
  __shared__ float h1[2][64];
  __shared__ float wfb2l[128];
  __shared__ float afA[2][68], afB[2][68];

  int tid = threadIdx.x;
  int g = tid >> 7, c = tid & 127;
  int bs0 = blockIdx.x * 2;
  int bs = bs0 + g;

  for (int e = tid; e < 2048; e += 256)
    ((float4*)WSPl)[e] = ((const float4*)WSPt)[e];
  if (tid < 128) wfb2l[tid] = wfb2[tid];
  __syncthreads();

  float acc = 0.f;
  for (int w = 0; w < W_; ++w) {
    int rg = bs * W_ + w;
    __syncthreads();
    if (c < 64) {
      float4 rc = *(const float4*)(rect + (size_t)rg * 4);
      float f0 = flags[rg * 2], f1 = flags[rg * 2 + 1];
      const float* w1 = sw1 + c * 6;
      float a = sb1[c] + w1[0]*rc.x + w1[1]*rc.y + w1[2]*rc.z + w1[3]*rc.w
                       + w1[4]*f0 + w1[5]*f1;
      h1[g][c] = fmaxf(a, 0.f);
    }
    __syncthreads();
    int t  = title_idx[rg];
    int ci = class_idx[rg];
    int p  = process_idx[rg];
    float v = TE2[(size_t)t * 128 + c] + CE2[(size_t)ci * 128 + c]
            + PE2[(size_t)p * 128 + c] + wfb2l[c];
    #pragma unroll 16
    for (int j = 0; j < 64; ++j) v += h1[g][j] * WSPl[j * 128 + c];
    acc += fmaxf(v, 0.f) * window_mask[rg];
  }
  {
    float v = acc * (1.f / (float)W_) + posenc(bs % S_, c);
    x[(size_t)bs * D_ + c] = v;
    xb[(size_t)bs * D_ + c] = __float2bfloat16(v);
  }

  // activity fusion -> cols 128..191 (2 bs, threads 0..127 active)
  int bl = tid >> 6, ln = tid & 63;
  bool act = (bl < 2);
  int bsg = bs0 + bl;
  __syncthreads();
  if (act && ln < 32) {
    float mx = mouse_pos[bsg * 2 + 0] * (1.f / 1920.f);
    float my = mouse_pos[bsg * 2 + 1] * (1.f / 1080.f);
    afA[bl][ln] = fmaxf(mw1[ln * 2] * mx + mw1[ln * 2 + 1] * my + mb1[ln], 0.f);
  }
  __syncthreads();
  float cv = 0.f;
  if (act) {
    if (ln < 32) {
      float a = mb2[ln];
      #pragma unroll 8
      for (int k = 0; k < 32; ++k) a += mw2[ln * 32 + k] * afA[bl][k];
      cv = a;
    } else if (ln < 48) {
      cv = act_emb[activity_type[bsg] * 16 + (ln - 32)];
    } else {
      cv = kbw[ln - 48] * keyboard_active[bsg] + kbb[ln - 48];
    }
  }
  __syncthreads();
  if (act) afB[bl][ln] = cv;
  __syncthreads();
  if (act) {
    float a = afb[ln];
    const float4* w4 = (const float4*)(afw + ln * 64);
    const float4* cp = (const float4*)&afB[bl][0];
    #pragma unroll
    for (int k4 = 0; k4 < 16; ++k4) {
      float4 ww = w4[k4], cc2 = cp[k4];
      a += ww.x*cc2.x + ww.y*cc2.y + ww.z*cc2.z + ww.w*cc2.w;
    }
    float v = fmaxf(a, 0.f);
    int cg = 128 + ln;
    float ovv = v + posenc(bsg % S_, cg);
    x[(size_t)bsg * D_ + cg] = ovv;
    xb[(size_t)bsg * D_ + cg] = __float2bfloat16(ovv);
  }
}

// ---------------------------------------------------------------------------
// Fused qkv + attention: one block per (b,h), 256 threads = 4 waves.
// Phase 1: Q/K/V head-slices via MFMA (M=128 padded S, N=3x32 tiles with 24
//   valid, K=192) from xb + streamed qkv weights; +bias; Q,K -> LDS row-major
//   (pitch 40, d 24..31 zeroed), V -> Vt[d][key].
// Phase 2: QK^T (4 m x 4 n), in-register softmax over 32-lane groups, mask
//   keys >= 100, P -> LDS bf16 (A-frag layout, pitch 136).
// Phase 3: PV (K=128 keys), divide by row-sum, store o head-slice.
// LDS = 64000 B exactly (Ps unioned over phase-1 Asl/Bsl). 2 blocks/CU.
// FIX R7: staging writes BOTH float4s per 16-element half-row (R6 wrote one —
// elements 8..15/24..31 were stale; same bug class as R3).
// ---------------------------------------------------------------------------
__global__ __launch_bounds__(256)
void qkvattn_kernel(const __hip_bfloat16* __restrict__ xb,
                    const __hip_bfloat16* __restrict__ Wq,   // 576x192 (layer)
                    const float* __restrict__ qb,            // 576 (layer)
                    __hip_bfloat16* __restrict__ o)
{
  __shared__ __align__(16) char smem[64000];
  __hip_bfloat16* Ps  = (__hip_bfloat16*)smem;             // 128*136 (phase 2/3)
  __hip_bfloat16* Asl = (__hip_bfloat16*)smem;             // 128*40  (phase 1)
  __hip_bfloat16* Bsl = (__hip_bfloat16*)(smem + 10240);   // 96*40   (phase 1)
  __hip_bfloat16* Qs  = (__hip_bfloat16*)(smem + 34816);   // 128*40
  __hip_bfloat16* Ks  = (__hip_bfloat16*)(smem + 45056);   // 128*40
  __hip_bfloat16* Vt  = (__hip_bfloat16*)(smem + 55296);   // 32*136

  int bh = blockIdx.x;
  int hh = bh & 7, b = bh >> 3;
  int tid = threadIdx.x, lane = tid & 63, w = tid >> 6;
  int m32 = lane & 31, half = lane >> 5;

  for (int e = tid; e < (32 * 136) / 8; e += 256)
    ((float4*)Vt)[e] = make_float4(0.f, 0.f, 0.f, 0.f);

  // ---- phase 1: qkv head-slice GEMM ----
  floatx16 acc[3];
  #pragma unroll
  for (int t = 0; t < 3; ++t)
    #pragma unroll
    for (int r = 0; r < 16; ++r) acc[t][r] = 0.f;

  for (int k0 = 0; k0 < D_; k0 += 32) {
    {
      int r = tid >> 1, h2 = tid & 1;
      int rr = r < S_ ? r : S_ - 1;
      const float4* s = (const float4*)&xb[(size_t)(b * S_ + rr) * D_ + k0 + h2 * 16];
      float4* d = (float4*)&Asl[r * 40 + h2 * 16];
      d[0] = s[0]; d[1] = s[1];
    }
    if (tid < 192) {
      int r = tid >> 1, h2 = tid & 1;
      int t = r >> 5, j = r & 31;
      float4 v0 = make_float4(0.f, 0.f, 0.f, 0.f), v1 = v0;
      if (j < DH_) {
        const float4* s =
            (const float4*)&Wq[(size_t)(t * D_ + hh * DH_ + j) * D_ + k0 + h2 * 16];
        v0 = s[0]; v1 = s[1];
      }
      float4* d = (float4*)&Bsl[r * 40 + h2 * 16];
      d[0] = v0; d[1] = v1;
    }
    __syncthreads();
    #pragma unroll
    for (int kc = 0; kc < 2; ++kc) {
      int ko = kc * 16 + half * 8;
      short8 a = *(const short8*)&Asl[(w * 32 + m32) * 40 + ko];
      #pragma unroll
      for (int t = 0; t < 3; ++t) {
        short8 bf = *(const short8*)&Bsl[(t * 32 + m32) * 40 + ko];
        acc[t] = __builtin_amdgcn_mfma_f32_32x32x16_bf16(a, bf, acc[t], 0, 0, 0);
      }
    }
    __syncthreads();
  }
  {
    bool dv = (m32 < DH_);
    float bq = dv ? qb[0 * D_ + hh * DH_ + m32] : 0.f;
    float bk = dv ? qb[1 * D_ + hh * DH_ + m32] : 0.f;
    float bv = dv ? qb[2 * D_ + hh * DH_ + m32] : 0.f;
    #pragma unroll
    for (int r = 0; r < 16; ++r) {
      int row = w * 32 + (r & 3) + 8 * (r >> 2) + 4 * half;
      Qs[row * 40 + m32] = __float2bfloat16(dv ? acc[0][r] + bq : 0.f);
      Ks[row * 40 + m32] = __float2bfloat16(dv ? acc[1][r] + bk : 0.f);
      if (dv) Vt[m32 * 136 + row] = __float2bfloat16(acc[2][r] + bv);
    }
  }
  __syncthreads();

  // ---- phase 2: QK^T + softmax ----
  floatx16 sc[4];
  #pragma unroll
  for (int nt = 0; nt < 4; ++nt)
    #pragma unroll
    for (int r = 0; r < 16; ++r) sc[nt][r] = 0.f;
  #pragma unroll
  for (int kc = 0; kc < 2; ++kc) {
    int ko = kc * 16 + half * 8;
    short8 a = *(const short8*)&Qs[(w * 32 + m32) * 40 + ko];
    #pragma unroll
    for (int nt = 0; nt < 4; ++nt) {
      short8 bf = *(const short8*)&Ks[(nt * 32 + m32) * 40 + ko];
      sc[nt] = __builtin_amdgcn_mfma_f32_32x32x16_bf16(a, bf, sc[nt], 0, 0, 0);
    }
  }
  const float scale = 0.20412414523193154f;  // 1/sqrt(24)
  float rinv[16];
  #pragma unroll
  for (int r = 0; r < 16; ++r) {
    float mx = -1e30f;
    #pragma unroll
    for (int nt = 0; nt < 4; ++nt) {
      float s = sc[nt][r] * scale;
      if (nt == 3 && m32 >= 4) s = -1e30f;   // keys >= 100
      sc[nt][r] = s;
      mx = fmaxf(mx, s);
    }
    #pragma unroll
    for (int off = 1; off < 32; off <<= 1) mx = fmaxf(mx, __shfl_xor(mx, off));
    float sum = 0.f;
    #pragma unroll
    for (int nt = 0; nt < 4; ++nt) {
      float e = expf(sc[nt][r] - mx);
      sc[nt][r] = e;
      sum += e;
    }
    #pragma unroll
    for (int off = 1; off < 32; off <<= 1) sum += __shfl_xor(sum, off);
    rinv[r] = 1.f / sum;
  }
  #pragma unroll
  for (int r = 0; r < 16; ++r) {
    int rowl = (r & 3) + 8 * (r >> 2) + 4 * half;
    #pragma unroll
    for (int nt = 0; nt < 4; ++nt)
      Ps[(w * 32 + rowl) * 136 + nt * 32 + m32] = __float2bfloat16(sc[nt][r]);
  }
  // Ps is wave-private (wave writes/reads its own 32 q-rows) — no barrier.

  // ---- phase 3: PV ----
  floatx16 ov;
  #pragma unroll
  for (int r = 0; r < 16; ++r) ov[r] = 0.f;
  #pragma unroll
  for (int kt = 0; kt < 8; ++kt) {
    int ko = kt * 16 + half * 8;
    short8 a = *(const short8*)&Ps[(w * 32 + m32) * 136 + ko];
    short8 bf = *(const short8*)&Vt[m32 * 136 + ko];
    ov = __builtin_amdgcn_mfma_f32_32x32x16_bf16(a, bf, ov, 0, 0, 0);
  }
  #pragma unroll
  for (int r = 0; r < 16; ++r) {
    int rowl = (r & 3) + 8 * (r >> 2) + 4 * half;
    int q = w * 32 + rowl;
    if (m32 < DH_ && q < S_)
      o[((size_t)(b * S_ + q)) * D_ + hh * DH_ + m32] =
          __float2bfloat16(ov[r] * rinv[r]);
  }
}

// ---------------------------------------------------------------------------
// out-proj + residual + LN (validated R5). 128 threads, BM=64 -> 200 blocks.
// ---------------------------------------------------------------------------
__global__ __launch_bounds__(128)
void outln_kernel(const __hip_bfloat16* __restrict__ A,
                  const __hip_bfloat16* __restrict__ Wt,
                  const float* __restrict__ bias,
                  const float* __restrict__ g, const float* __restrict__ bvec,
                  float* __restrict__ x, __hip_bfloat16* __restrict__ xb)
{
  __shared__ __align__(16) __hip_bfloat16 Asl[64 * 40];
  __shared__ __align__(16) __hip_bfloat16 Bsl[192 * 40];
  int tid = threadIdx.x, lane = tid & 63, w = tid >> 6;
  int m32 = lane & 31, half = lane >> 5;
  int bm = blockIdx.x * 64;

  floatx16 acc[6];
  #pragma unroll
  for (int nt = 0; nt < 6; ++nt)
    #pragma unroll
    for (int r = 0; r < 16; ++r) acc[nt][r] = 0.f;

  for (int k0 = 0; k0 < D_; k0 += 32) {
    {
      int r = tid >> 1, h = tid & 1;
      const float4* s = (const float4*)(A + (size_t)(bm + r) * D_ + k0 + h * 16);
      float4* d = (float4*)&Asl[r * 40 + h * 16];
      d[0] = s[0]; d[1] = s[1];
    }
    for (int e = tid; e < 384; e += 128) {
      int r = e >> 1, h = e & 1;
      const float4* s = (const float4*)(Wt + (size_t)r * D_ + k0 + h * 16);
      float4* d = (float4*)&Bsl[r * 40 + h * 16];
      d[0] = s[0]; d[1] = s[1];
    }
    __syncthreads();
    #pragma unroll
    for (int kc = 0; kc < 2; ++kc) {
      int ko = kc * 16 + half * 8;
      short8 a = *(const short8*)&Asl[(w * 32 + m32) * 40 + ko];
      #pragma unroll
      for (int nt = 0; nt < 6; ++nt) {
        short8 bf = *(const short8*)&Bsl[(nt * 32 + m32) * 40 + ko];
        acc[nt] = __builtin_amdgcn_mfma_f32_32x32x16_bf16(a, bf, acc[nt], 0, 0, 0);
      }
    }
    __syncthreads();
  }

  float cbias[6], cg[6], cb2[6];
  #pragma unroll
  for (int nt = 0; nt < 6; ++nt) {
    int col = nt * 32 + m32;
    cbias[nt] = bias[col]; cg[nt] = g[col]; cb2[nt] = bvec[col];
  }
  int rowbase = bm + w * 32 + 4 * half;
  #pragma unroll
  for (int r = 0; r < 16; ++r) {
    int row = rowbase + (r & 3) + 8 * (r >> 2);
    float part = 0.f;
    #pragma unroll
    for (int nt = 0; nt < 6; ++nt) {
      int col = nt * 32 + m32;
      float t = acc[nt][r] + cbias[nt] + x[(size_t)row * D_ + col];
      acc[nt][r] = t;
      part += t;
    }
    #pragma unroll
    for (int off = 1; off < 32; off <<= 1) part += __shfl_xor(part, off);
    float mean = part * (1.f / (float)D_);
    float sq = 0.f;
    #pragma unroll
    for (int nt = 0; nt < 6; ++nt) { float dd = acc[nt][r] - mean; sq += dd * dd; }
    #pragma unroll
    for (int off = 1; off < 32; off <<= 1) sq += __shfl_xor(sq, off);
    float inv = rsqrtf(sq * (1.f / (float)D_) + 1e-5f);
    #pragma unroll
    for (int nt = 0; nt < 6; ++nt) {
      int col = nt * 32 + m32;
      float ovv = (acc[nt][r] - mean) * inv * cg[nt] + cb2[nt];
      x[(size_t)row * D_ + col] = ovv;
      xb[(size_t)row * D_ + col] = __float2bfloat16(ovv);
    }
  }
}

// ---------------------------------------------------------------------------
// ff1 + ff2 + residual + LN (validated R4/R5). 256 threads, BM=64.
// ---------------------------------------------------------------------------
__global__ __launch_bounds__(256)
void ffln_kernel(const __hip_bfloat16* __restrict__ xbi,
                 const __hip_bfloat16* __restrict__ W1, const float* __restrict__ b1,
                 const __hip_bfloat16* __restrict__ W2, const float* __restrict__ b2,
                 const float* __restrict__ g, const float* __restrict__ bvec,
                 float* __restrict__ x, __hip_bfloat16* __restrict__ xb)
{
  __shared__ __align__(16) __hip_bfloat16 C1[64 * 260];
  __shared__ __align__(16) __hip_bfloat16 Asl[64 * 40];
  __shared__ __align__(16) __hip_bfloat16 Bsl[256 * 40];
  __shared__ float psum[64][2];
  __shared__ float psq[64][2];
  int tid = threadIdx.x, lane = tid & 63, w = tid >> 6;
  int m32 = lane & 31, half = lane >> 5;
  int mt = w & 1, ng = w >> 1;
  int bm = blockIdx.x * 64;

  floatx16 acc1[4];
  #pragma unroll
  for (int j = 0; j < 4; ++j)
    #pragma unroll
    for (int r = 0; r < 16; ++r) acc1[j][r] = 0.f;

  for (int k0 = 0; k0 < D_; k0 += 32) {
    if (tid < 128) {
      int r = tid >> 1, h = tid & 1;
      const float4* s = (const float4*)(xbi + (size_t)(bm + r) * D_ + k0 + h * 16);
      float4* d = (float4*)&Asl[r * 40 + h * 16];
      d[0] = s[0]; d[1] = s[1];
    }
    for (int e = tid; e < 512; e += 256) {
      int r = e >> 1, h = e & 1;
      const float4* s = (const float4*)(W1 + (size_t)r * D_ + k0 + h * 16);
      float4* d = (float4*)&Bsl[r * 40 + h * 16];
      d[0] = s[0]; d[1] = s[1];
    }
    __syncthreads();
    #pragma unroll
    for (int kc = 0; kc < 2; ++kc) {
      int ko = kc * 16 + half * 8;
      short8 a = *(const short8*)&Asl[(mt * 32 + m32) * 40 + ko];
      #pragma unroll
      for (int j = 0; j < 4; ++j) {
        short8 bf = *(const short8*)&Bsl[((ng * 4 + j) * 32 + m32) * 40 + ko];
        acc1[j] = __builtin_amdgcn_mfma_f32_32x32x16_bf16(a, bf, acc1[j], 0, 0, 0);
      }
    }
    __syncthreads();
  }
  {
    int rowb = mt * 32 + 4 * half;
    #pragma unroll
    for (int j = 0; j < 4; ++j) {
      int col = (ng * 4 + j) * 32 + m32;
      float cb = b1[col];
      #pragma unroll
      for (int r = 0; r < 16; ++r) {
        int row = rowb + (r & 3) + 8 * (r >> 2);
        C1[row * 260 + col] = __float2bfloat16(fmaxf(acc1[j][r] + cb, 0.f));
      }
    }
  }
  __syncthreads();

  floatx16 acc2[3];
  #pragma unroll
  for (int j = 0; j < 3; ++j)
    #pragma unroll
    for (int r = 0; r < 16; ++r) acc2[j][r] = 0.f;

  for (int k0 = 0; k0 < DFF_; k0 += 32) {
    for (int e = tid; e < 384; e += 256) {
      int r = e >> 1, h = e & 1;
      const float4* s = (const float4*)(W2 + (size_t)r * DFF_ + k0 + h * 16);
      float4* d = (float4*)&Bsl[r * 40 + h * 16];
      d[0] = s[0]; d[1] = s[1];
    }
    __syncthreads();
    #pragma unroll
    for (int kc = 0; kc < 2; ++kc) {
      int ko = kc * 16 + half * 8;
      const __hip_bfloat16* cp = &C1[(mt * 32 + m32) * 260 + k0 + ko];
      short8 a;
      {
        typedef short short4v __attribute__((ext_vector_type(4)));
        short4v lo = *(const short4v*)cp;
        short4v hi = *(const short4v*)(cp + 4);
        a[0]=lo[0]; a[1]=lo[1]; a[2]=lo[2]; a[3]=lo[3];
        a[4]=hi[0]; a[5]=hi[1]; a[6]=hi[2]; a[7]=hi[3];
      }
      #pragma unroll
      for (int j = 0; j < 3; ++j) {
        short8 bf = *(const short8*)&Bsl[((ng * 3 + j) * 32 + m32) * 40 + ko];
        acc2[j] = __builtin_amdgcn_mfma_f32_32x32x16_bf16(a, bf, acc2[j], 0, 0, 0);
      }
    }
    __syncthreads();
  }

  int rowb = mt * 32 + 4 * half;
  #pragma unroll
  for (int r = 0; r < 16; ++r) {
    int rl = rowb + (r & 3) + 8 * (r >> 2);
    int row = bm + rl;
    float p = 0.f;
    #pragma unroll
    for (int j = 0; j < 3; ++j) {
      int col = (ng * 3 + j) * 32 + m32;
      float t = acc2[j][r] + b2[col] + x[(size_t)row * D_ + col];
      acc2[j][r] = t;
      p += t;
    }
    #pragma unroll
    for (int off = 1; off < 32; off <<= 1) p += __shfl_xor(p, off);
    if (m32 == 0) psum[rl][ng] = p;
  }
  __syncthreads();
  float mean[16];
  #pragma unroll
  for (int r = 0; r < 16; ++r) {
    int rl = rowb + (r & 3) + 8 * (r >> 2);
    mean[r] = (psum[rl][0] + psum[rl][1]) * (1.f / (float)D_);
  }
  #pragma unroll
  for (int r = 0; r < 16; ++r) {
    int rl = rowb + (r & 3) + 8 * (r >> 2);
    float s = 0.f;
    #pragma unroll
    for (int j = 0; j < 3; ++j) { float dd = acc2[j][r] - mean[r]; s += dd * dd; }
    #pragma unroll
    for (int off = 1; off < 32; off <<= 1) s += __shfl_xor(s, off);
    if (m32 == 0) psq[rl][ng] = s;
  }
  __syncthreads();
  #pragma unroll
  for (int r = 0; r < 16; ++r) {
    int rl = rowb + (r & 3) + 8 * (r >> 2);
    int row = bm + rl;
    float inv = rsqrtf((psq[rl][0] + psq[rl][1]) * (1.f / (float)D_) + 1e-5f);
    #pragma unroll
    for (int j = 0; j < 3; ++j) {
      int col = (ng * 3 + j) * 32 + m32;
      float ovv = (acc2[j][r] - mean[r]) * inv * g[col] + bvec[col];
      x[(size_t)row * D_ + col] = ovv;
      xb[(size_t)row * D_ + col] = __float2bfloat16(ovv);
    }
  }
}

// ---------------------------------------------------------------------------
// Head (fp32): one block per (w,b) slot.
// ---------------------------------------------------------------------------
__global__ __launch_bounds__(256)
void head_kernel(const float* __restrict__ x, const float* __restrict__ noise,
                 const float* __restrict__ pw1, const float* __restrict__ pb1,
                 const float* __restrict__ pw2, const float* __restrict__ pb2,
                 const float* __restrict__ ew1, const float* __restrict__ eb1,
                 const float* __restrict__ ew2, const float* __restrict__ eb2,
                 float* __restrict__ out)
{
  int idx = blockIdx.x;
  int b = idx & 127, w = idx >> 7;
  int tid = threadIdx.x;
  __shared__ float slot[192];
  __shared__ float ph[256];
  __shared__ float eh[128];
  if (tid < 192)
    slot[tid] = x[((size_t)b * S_ + (S_ - 1)) * D_ + tid]
              + noise[((size_t)w * B_ + b) * D_ + tid] * 0.1f;
  __syncthreads();
  {
    const float4* wr = (const float4*)(pw1 + (size_t)tid * D_);
    const float4* sp = (const float4*)slot;
    float a = pb1[tid];
    #pragma unroll 12
    for (int k = 0; k < 48; ++k) {
      float4 wv = wr[k], sv = sp[k];
      a += wv.x*sv.x + wv.y*sv.y + wv.z*sv.z + wv.w*sv.w;
    }
    ph[tid] = fmaxf(a, 0.f);
  }
  if (tid < 128) {
    const float4* wr = (const float4*)(ew1 + (size_t)tid * D_);
    const float4* sp = (const float4*)slot;
    float a = eb1[tid];
    #pragma unroll 12
    for (int k = 0; k < 48; ++k) {
      float4 wv = wr[k], sv = sp[k];
      a += wv.x*sv.x + wv.y*sv.y + wv.z*sv.z + wv.w*sv.w;
    }
    eh[tid] = fmaxf(a, 0.f);
  }
  __syncthreads();
  if (tid < 4) {
    float a = pb2[tid];
    const float4* wr = (const float4*)(pw2 + tid * 256);
    const float4* pp = (const float4*)ph;
    for (int k = 0; k < 64; ++k) {
      float4 wv = wr[k], pv = pp[k];
      a += wv.x*pv.x + wv.y*pv.y + wv.z*pv.z + wv.w*pv.w;
    }
    out[((size_t)b * W_ + w) * 4 + tid] = a;
  }
  if (tid == 4) {
    float a = eb2[0];
    const float4* wr = (const float4*)ew2;
    const float4* pp = (const float4*)eh;
    for (int k = 0; k < 32; ++k) {
      float4 wv = wr[k], pv = pp[k];
      a += wv.x*pv.x + wv.y*pv.y + wv.z*pv.z + wv.w*pv.w;
    }
    out[(size_t)B_ * W_ * 4 + (size_t)b * W_ + w] = 1.f / (1.f + expf(-a));
  }
}

// ---------------------------------------------------------------------------
extern "C" void kernel_launch(void* const* d_in, const int* in_sizes, int n_in,
                              void* d_out, int out_size, void* d_ws, size_t ws_size,
                              hipStream_t stream)
{
  const int*   title_idx       = (const int*)  d_in[0];
  const int*   class_idx       = (const int*)  d_in[1];
  const int*   process_idx     = (const int*)  d_in[2];
  const int*   activity_type   = (const int*)  d_in[3];
  const float* mouse_pos       = (const float*)d_in[4];
  const float* rect            = (const float*)d_in[5];
  const float* flags           = (const float*)d_in[6];
  const float* keyboard_active = (const float*)d_in[7];
  const float* window_mask     = (const float*)d_in[8];
  const float* noise           = (const float*)d_in[9];
  const float* title_emb       = (const float*)d_in[10];
  const float* class_emb       = (const float*)d_in[11];
  const float* process_emb     = (const float*)d_in[12];
  const float* spatial_w1      = (const float*)d_in[13];
  const float* spatial_b1      = (const float*)d_in[14];
  const float* spatial_w2      = (const float*)d_in[15];
  const float* spatial_b2      = (const float*)d_in[16];
  const float* wfuse_w         = (const float*)d_in[17];
  const float* wfuse_b         = (const float*)d_in[18];
  const float* mouse_w1        = (const float*)d_in[19];
  const float* mouse_b1        = (const float*)d_in[20];
  const float* mouse_w2        = (const float*)d_in[21];
  const float* mouse_b2        = (const float*)d_in[22];
  const float* act_emb         = (const float*)d_in[23];
  const float* kbd_w           = (const float*)d_in[24];
  const float* kbd_b           = (const float*)d_in[25];
  const float* afuse_w         = (const float*)d_in[26];
  const float* afuse_b         = (const float*)d_in[27];
  const float* qkv_w           = (const float*)d_in[28];
  const float* qkv_b           = (const float*)d_in[29];
  const float* out_w           = (const float*)d_in[30];
  const float* out_b           = (const float*)d_in[31];
  const float* ff1_w           = (const float*)d_in[32];
  const float* ff1_b           = (const float*)d_in[33];
  const float* ff2_w           = (const float*)d_in[34];
  const float* ff2_b           = (const float*)d_in[35];
  const float* ln1_g           = (const float*)d_in[36];
  const float* ln1_b           = (const float*)d_in[37];
  const float* ln2_g           = (const float*)d_in[38];
  const float* ln2_b           = (const float*)d_in[39];
  const float* proj_w1         = (const float*)d_in[40];
  const float* proj_b1         = (const float*)d_in[41];
  const float* proj_w2         = (const float*)d_in[42];
  const float* proj_b2         = (const float*)d_in[43];
  const float* ex_w1           = (const float*)d_in[44];
  const float* ex_b1           = (const float*)d_in[45];
  const float* ex_w2           = (const float*)d_in[46];
  const float* ex_b2           = (const float*)d_in[47];

  float* out = (float*)d_out;

  // workspace layout
  float* x = (float*)d_ws;                                      // BS*192 f32
  __hip_bfloat16* xb   = (__hip_bfloat16*)(x + (size_t)BS_ * D_);
  __hip_bfloat16* attb = xb   + (size_t)BS_ * D_;
  __hip_bfloat16* wqb  = attb + (size_t)BS_ * D_;               // 6*576*192
  __hip_bfloat16* wob  = wqb  + (size_t)L_ * THREED_ * D_;      // 6*192*192
  __hip_bfloat16* wf1b = wob  + (size_t)L_ * D_ * D_;           // 6*256*192
  __hip_bfloat16* wf2b = wf1b + (size_t)L_ * DFF_ * D_;         // 6*192*256
  float* TE2  = (float*)(wf2b + (size_t)L_ * D_ * DFF_);        // 1000*128
  float* CE2  = TE2  + 1000 * 128;                              // 500*128
  float* PE2  = CE2  + 500 * 128;                               // 1000*128
  float* WSPt = PE2  + 1000 * 128;                              // 64*128
  float* wfb2 = WSPt + 64 * 128;                                // 128
  (void)ws_size; (void)n_in; (void)in_sizes; (void)out_size;

  convert4_kernel<<<720, 256, 0, stream>>>(qkv_w, wqb, out_w, wob,
                                           ff1_w, wf1b, ff2_w, wf2b);
  prep_kernel<<<1283, 256, 0, stream>>>(title_emb, class_emb, process_emb,
                                        wfuse_w, wfuse_b, spatial_w2, spatial_b2,
                                        TE2, CE2, PE2, WSPt, wfb2);
  encode2_kernel<<<BS_ / 2, 256, 0, stream>>>(
      title_idx, class_idx, process_idx, activity_type, mouse_pos, rect, flags,
      keyboard_active, window_mask, spatial_w1, spatial_b1,
      TE2, CE2, PE2, WSPt, wfb2,
      mouse_w1, mouse_b1, mouse_w2, mouse_b2, act_emb, kbd_w, kbd_b,
      afuse_w, afuse_b, x, xb);

  for (int l = 0; l < L_; ++l) {
    qkvattn_kernel<<<B_ * H_, 256, 0, stream>>>(
        xb, wqb + (size_t)l * THREED_ * D_, qkv_b + (size_t)l * THREED_, attb);
    outln_kernel<<<BS_ / 64, 128, 0, stream>>>(
        attb, wob + (size_t)l * D_ * D_, out_b + (size_t)l * D_,
        ln1_g + (size_t)l * D_, ln1_b + (size_t)l * D_, x, xb);
    ffln_kernel<<<BS_ / 64, 256, 0, stream>>>(
        xb, wf1b + (size_t)l * DFF_ * D_, ff1_b + (size_t)l * DFF_,
        wf2b + (size_t)l * D_ * DFF_, ff2_b + (size_t)l * D_,
        ln2_g + (size_t)l * D_, ln2_b + (size_t)l * D_, x, xb);
  }

  head_kernel<<<W_ * B_, 256, 0, stream>>>(
      x, noise, proj_w1, proj_b1, proj_w2, proj_b2,
      ex_w1, ex_b1, ex_w2, ex_b2, out);
}

// Round 9
// 928.988 us; speedup vs baseline: 1.7634x; 1.0953x over previous
//
#include <hip/hip_runtime.h>
#include <hip/hip_bf16.h>
#include <math.h>

#define B_ 128
#define S_ 100
#define W_ 20
#define D_ 192
#define L_ 6
#define H_ 8
#define DFF_ 256
#define DH_ 24
#define BS_ (B_*S_)
#define THREED_ 576

typedef short short8 __attribute__((ext_vector_type(8)));
typedef float floatx16 __attribute__((ext_vector_type(16)));

__device__ __forceinline__ float posenc(int s, int c) {
  float freq = expf(-logf(10000.f) * (float)(2 * (c >> 1)) / (float)D_);
  float ang = (float)s * freq;
  return (c & 1) ? cosf(ang) : sinf(ang);
}

// ---------------------------------------------------------------------------
// Merged weight conversion + encoder precompute. One launch, 2003 blocks:
//   blocks    0..719  : fp32->bf16 conversion (qkv 324 | out 108 | ff1 144 | ff2 144)
//   blocks  720..2002 : prep (TE2/CE2/PE2 1250 | WSPt 32 | wfb2 1)
// ---------------------------------------------------------------------------
__global__ __launch_bounds__(256)
void convertprep_kernel(
    const float* __restrict__ s0, __hip_bfloat16* __restrict__ d0,
    const float* __restrict__ s1, __hip_bfloat16* __restrict__ d1,
    const float* __restrict__ s2, __hip_bfloat16* __restrict__ d2,
    const float* __restrict__ s3, __hip_bfloat16* __restrict__ d3,
    const float* __restrict__ te, const float* __restrict__ ce,
    const float* __restrict__ pe, const float* __restrict__ wfw,
    const float* __restrict__ wfb, const float* __restrict__ sw2,
    const float* __restrict__ sb2,
    float* __restrict__ TE2, float* __restrict__ CE2,
    float* __restrict__ PE2, float* __restrict__ WSPt,
    float* __restrict__ wfb2)
{
  int b = blockIdx.x, tid = threadIdx.x;
  if (b < 720) {
    const float* s; __hip_bfloat16* d; int base;
    if      (b < 324) { s = s0; d = d0; base = b; }
    else if (b < 432) { s = s1; d = d1; base = b - 324; }
    else if (b < 576) { s = s2; d = d2; base = b - 432; }
    else              { s = s3; d = d3; base = b - 576; }
    int i = (base * 256 + tid) * 8;
    float4 v0 = *(const float4*)(s + i);
    float4 v1 = *(const float4*)(s + i + 4);
    __hip_bfloat162* d2p = (__hip_bfloat162*)(d + i);
    d2p[0] = __float22bfloat162_rn(make_float2(v0.x, v0.y));
    d2p[1] = __float22bfloat162_rn(make_float2(v0.z, v0.w));
    d2p[2] = __float22bfloat162_rn(make_float2(v1.x, v1.y));
    d2p[3] = __float22bfloat162_rn(make_float2(v1.z, v1.w));
    return;
  }
  int blk = b - 720;
  if (blk < 1250) {
    int item = blk * 256 + tid;          // < 320000
    int v = item >> 7, o = item & 127;
    const float* src; float* dst; int base, vv;
    if (v < 1000)      { src = te; dst = TE2; base = 0;  vv = v; }
    else if (v < 1500) { src = ce; dst = CE2; base = 32; vv = v - 1000; }
    else               { src = pe; dst = PE2; base = 64; vv = v - 1500; }
    float a = 0.f;
    #pragma unroll 8
    for (int k = 0; k < 32; ++k) a += src[vv * 32 + k] * wfw[o * 128 + base + k];
    dst[vv * 128 + o] = a;
  } else if (blk < 1282) {
    int item = (blk - 1250) * 256 + tid; // < 8192
    int j = item >> 7, o = item & 127;
    float a = 0.f;
    #pragma unroll 8
    for (int k = 0; k < 32; ++k) a += wfw[o * 128 + 96 + k] * sw2[k * 64 + j];
    WSPt[j * 128 + o] = a;
  } else if (tid < 128) {
    float a = wfb[tid];
    #pragma unroll 8
    for (int k = 0; k < 32; ++k) a += wfw[tid * 128 + 96 + k] * sb2[k];
    wfb2[tid] = a;
  }
}

// ---------------------------------------------------------------------------
// Encoder v3: 2 bs per block, 256 threads (2 groups x 128 cols).
// R8 restructure vs encode2 (which was 315 us, VALUBusy 32%):
//  - ALL spatial-MLP h1 values hoisted into LDS upfront (2x20x64), ONE barrier
//    instead of 40 (2 per window).
//  - WSP held in 64 registers per thread (unrolled j) instead of LDS; inner
//    loop is broadcast ds_read_b128 of h1 (16/window) + 64 FMA.
//  - idx/mask staged in LDS so the main loop has no serial scalar loads.
// LDS ~13 KB.
// ---------------------------------------------------------------------------
__global__ __launch_bounds__(256)
void encode3_kernel(
    const int* __restrict__ title_idx, const int* __restrict__ class_idx,
    const int* __restrict__ process_idx, const int* __restrict__ activity_type,
    const float* __restrict__ mouse_pos, const float* __restrict__ rect,
    const float* __restrict__ flags, const float* __restrict__ keyboard_active,
    const float* __restrict__ window_mask,
    const float* __restrict__ sw1, const float* __restrict__ sb1,
    const float* __restrict__ TE2, const float* __restrict__ CE2,
    const float* __restrict__ PE2, const float* __restrict__ WSPt,
    const float* __restrict__ wfb2,
    const float* __restrict__ mw1, const float* __restrict__ mb1,
    const float* __restrict__ mw2, const float* __restrict__ mb2,
    const float* __restrict__ act_emb, const float* __restrict__ kbw,
    const float* __restrict__ kbb,
    const float* __restrict__ afw, const float* __restrict__ afb,
    float* __restrict__ x, __hip_bfloat16* __restrict__ xb)
{
  __shared__ float h1all[2][20][64];   // 10240 B
  __shared__ float wfb2l[128];
  __shared__ int   idxS[2][20][3];
  __shared__ float maskS[2][20];
  __shared__ float afA[2][68], afB[2][68];

  int tid = threadIdx.x;
  int g = tid >> 7, c = tid & 127;
  int bs0 = blockIdx.x * 2;
  int bs = bs0 + g;

  // WSP column -> registers (64 coalesced loads, L2-resident)
  float wsp[64];
  #pragma unroll
  for (int j = 0; j < 64; ++j) wsp[j] = WSPt[j * 128 + c];

  // stage idx (120 items), mask (40), wfb2l (128)
  if (tid < 120) {
    int g2 = tid / 60, rem = tid % 60;
    int which = rem / 20, w = rem % 20;
    int rg = (bs0 + g2) * W_ + w;
    const int* src = (which == 0) ? title_idx : (which == 1) ? class_idx : process_idx;
    idxS[g2][w][which] = src[rg];
  } else if (tid < 160) {
    int e = tid - 120;
    int g2 = e / 20, w = e % 20;
    maskS[g2][w] = window_mask[(bs0 + g2) * W_ + w];
  }
  if (tid >= 128) wfb2l[tid - 128] = wfb2[tid - 128];
  // h1all: 2560 items, 10 per thread
  for (int e = tid; e < 2560; e += 256) {
    int g2 = e / 1280, rem = e - g2 * 1280;
    int w = rem >> 6, j = rem & 63;
    int rg = (bs0 + g2) * W_ + w;
    float4 rc = *(const float4*)(rect + (size_t)rg * 4);
    float f0 = flags[rg * 2], f1 = flags[rg * 2 + 1];
    const float* w1 = sw1 + j * 6;
    float a = sb1[j] + w1[0]*rc.x + w1[1]*rc.y + w1[2]*rc.z + w1[3]*rc.w
                     + w1[4]*f0 + w1[5]*f1;
    h1all[g2][w][j] = fmaxf(a, 0.f);
  }
  __syncthreads();   // the ONLY barrier before the main loop

  float acc = 0.f;
  for (int w = 0; w < W_; ++w) {
    int t  = idxS[g][w][0];
    int ci = idxS[g][w][1];
    int p  = idxS[g][w][2];
    float v = TE2[(size_t)t * 128 + c] + CE2[(size_t)ci * 128 + c]
            + PE2[(size_t)p * 128 + c] + wfb2l[c];
    const float4* hp = (const float4*)&h1all[g][w][0];
    #pragma unroll
    for (int j4 = 0; j4 < 16; ++j4) {
      float4 h = hp[j4];
      v += h.x * wsp[4*j4] + h.y * wsp[4*j4+1] + h.z * wsp[4*j4+2] + h.w * wsp[4*j4+3];
    }
    acc += fmaxf(v, 0.f) * maskS[g][w];
  }
  {
    float v = acc * (1.f / (float)W_) + posenc(bs % S_, c);
    x[(size_t)bs * D_ + c] = v;
    xb[(size_t)bs * D_ + c] = __float2bfloat16(v);
  }

  // activity fusion -> cols 128..191 (validated structure)
  int bl = tid >> 6, ln = tid & 63;
  bool act = (bl < 2);
  int bsg = bs0 + bl;
  __syncthreads();
  if (act && ln < 32) {
    float mx = mouse_pos[bsg * 2 + 0] * (1.f / 1920.f);
    float my = mouse_pos[bsg * 2 + 1] * (1.f / 1080.f);
    afA[bl][ln] = fmaxf(mw1[ln * 2] * mx + mw1[ln * 2 + 1] * my + mb1[ln], 0.f);
  }
  __syncthreads();
  float cv = 0.f;
  if (act) {
    if (ln < 32) {
      float a = mb2[ln];
      #pragma unroll 8
      for (int k = 0; k < 32; ++k) a += mw2[ln * 32 + k] * afA[bl][k];
      cv = a;
    } else if (ln < 48) {
      cv = act_emb[activity_type[bsg] * 16 + (ln - 32)];
    } else {
      cv = kbw[ln - 48] * keyboard_active[bsg] + kbb[ln - 48];
    }
  }
  __syncthreads();
  if (act) afB[bl][ln] = cv;
  __syncthreads();
  if (act) {
    float a = afb[ln];
    const float4* w4 = (const float4*)(afw + ln * 64);
    const float4* cp = (const float4*)&afB[bl][0];
    #pragma unroll
    for (int k4 = 0; k4 < 16; ++k4) {
      float4 ww = w4[k4], cc2 = cp[k4];
      a += ww.x*cc2.x + ww.y*cc2.y + ww.z*cc2.z + ww.w*cc2.w;
    }
    float v = fmaxf(a, 0.f);
    int cg = 128 + ln;
    float ovv = v + posenc(bsg % S_, cg);
    x[(size_t)bsg * D_ + cg] = ovv;
    xb[(size_t)bsg * D_ + cg] = __float2bfloat16(ovv);
  }
}

// ---------------------------------------------------------------------------
// Fused qkv + attention (validated R7). One block per (b,h), 256 threads.
// ---------------------------------------------------------------------------
__global__ __launch_bounds__(256)
void qkvattn_kernel(const __hip_bfloat16* __restrict__ xb,
                    const __hip_bfloat16* __restrict__ Wq,   // 576x192 (layer)
                    const float* __restrict__ qb,            // 576 (layer)
                    __hip_bfloat16* __restrict__ o)
{
  __shared__ __align__(16) char smem[64000];
  __hip_bfloat16* Ps  = (__hip_bfloat16*)smem;             // 128*136 (phase 2/3)
  __hip_bfloat16* Asl = (__hip_bfloat16*)smem;             // 128*40  (phase 1)
  __hip_bfloat16* Bsl = (__hip_bfloat16*)(smem + 10240);   // 96*40   (phase 1)
  __hip_bfloat16* Qs  = (__hip_bfloat16*)(smem + 34816);   // 128*40
  __hip_bfloat16* Ks  = (__hip_bfloat16*)(smem + 45056);   // 128*40
  __hip_bfloat16* Vt  = (__hip_bfloat16*)(smem + 55296);   // 32*136

  int bh = blockIdx.x;
  int hh = bh & 7, b = bh >> 3;
  int tid = threadIdx.x, lane = tid & 63, w = tid >> 6;
  int m32 = lane & 31, half = lane >> 5;

  for (int e = tid; e < (32 * 136) / 8; e += 256)
    ((float4*)Vt)[e] = make_float4(0.f, 0.f, 0.f, 0.f);

  // ---- phase 1: qkv head-slice GEMM ----
  floatx16 acc[3];
  #pragma unroll
  for (int t = 0; t < 3; ++t)
    #pragma unroll
    for (int r = 0; r < 16; ++r) acc[t][r] = 0.f;

  for (int k0 = 0; k0 < D_; k0 += 32) {
    {
      int r = tid >> 1, h2 = tid & 1;
      int rr = r < S_ ? r : S_ - 1;
      const float4* s = (const float4*)&xb[(size_t)(b * S_ + rr) * D_ + k0 + h2 * 16];
      float4* d = (float4*)&Asl[r * 40 + h2 * 16];
      d[0] = s[0]; d[1] = s[1];
    }
    if (tid < 192) {
      int r = tid >> 1, h2 = tid & 1;
      int t = r >> 5, j = r & 31;
      float4 v0 = make_float4(0.f, 0.f, 0.f, 0.f), v1 = v0;
      if (j < DH_) {
        const float4* s =
            (const float4*)&Wq[(size_t)(t * D_ + hh * DH_ + j) * D_ + k0 + h2 * 16];
        v0 = s[0]; v1 = s[1];
      }
      float4* d = (float4*)&Bsl[r * 40 + h2 * 16];
      d[0] = v0; d[1] = v1;
    }
    __syncthreads();
    #pragma unroll
    for (int kc = 0; kc < 2; ++kc) {
      int ko = kc * 16 + half * 8;
      short8 a = *(const short8*)&Asl[(w * 32 + m32) * 40 + ko];
      #pragma unroll
      for (int t = 0; t < 3; ++t) {
        short8 bf = *(const short8*)&Bsl[(t * 32 + m32) * 40 + ko];
        acc[t] = __builtin_amdgcn_mfma_f32_32x32x16_bf16(a, bf, acc[t], 0, 0, 0);
      }
    }
    __syncthreads();
  }
  {
    bool dv = (m32 < DH_);
    float bq = dv ? qb[0 * D_ + hh * DH_ + m32] : 0.f;
    float bk = dv ? qb[1 * D_ + hh * DH_ + m32] : 0.f;
    float bv = dv ? qb[2 * D_ + hh * DH_ + m32] : 0.f;
    #pragma unroll
    for (int r = 0; r < 16; ++r) {
      int row = w * 32 + (r & 3) + 8 * (r >> 2) + 4 * half;
      Qs[row * 40 + m32] = __float2bfloat16(dv ? acc[0][r] + bq : 0.f);
      Ks[row * 40 + m32] = __float2bfloat16(dv ? acc[1][r] + bk : 0.f);
      if (dv) Vt[m32 * 136 + row] = __float2bfloat16(acc[2][r] + bv);
    }
  }
  __syncthreads();

  // ---- phase 2: QK^T + softmax ----
  floatx16 sc[4];
  #pragma unroll
  for (int nt = 0; nt < 4; ++nt)
    #pragma unroll
    for (int r = 0; r < 16; ++r) sc[nt][r] = 0.f;
  #pragma unroll
  for (int kc = 0; kc < 2; ++kc) {
    int ko = kc * 16 + half * 8;
    short8 a = *(const short8*)&Qs[(w * 32 + m32) * 40 + ko];
    #pragma unroll
    for (int nt = 0; nt < 4; ++nt) {
      short8 bf = *(const short8*)&Ks[(nt * 32 + m32) * 40 + ko];
      sc[nt] = __builtin_amdgcn_mfma_f32_32x32x16_bf16(a, bf, sc[nt], 0, 0, 0);
    }
  }
  const float scale = 0.20412414523193154f;  // 1/sqrt(24)
  float rinv[16];
  #pragma unroll
  for (int r = 0; r < 16; ++r) {
    float mx = -1e30f;
    #pragma unroll
    for (int nt = 0; nt < 4; ++nt) {
      float s = sc[nt][r] * scale;
      if (nt == 3 && m32 >= 4) s = -1e30f;   // keys >= 100
      sc[nt][r] = s;
      mx = fmaxf(mx, s);
    }
    #pragma unroll
    for (int off = 1; off < 32; off <<= 1) mx = fmaxf(mx, __shfl_xor(mx, off));
    float sum = 0.f;
    #pragma unroll
    for (int nt = 0; nt < 4; ++nt) {
      float e = expf(sc[nt][r] - mx);
      sc[nt][r] = e;
      sum += e;
    }
    #pragma unroll
    for (int off = 1; off < 32; off <<= 1) sum += __shfl_xor(sum, off);
    rinv[r] = 1.f / sum;
  }
  #pragma unroll
  for (int r = 0; r < 16; ++r) {
    int rowl = (r & 3) + 8 * (r >> 2) + 4 * half;
    #pragma unroll
    for (int nt = 0; nt < 4; ++nt)
      Ps[(w * 32 + rowl) * 136 + nt * 32 + m32] = __float2bfloat16(sc[nt][r]);
  }
  // Ps is wave-private — no barrier.

  // ---- phase 3: PV ----
  floatx16 ov;
  #pragma unroll
  for (int r = 0; r < 16; ++r) ov[r] = 0.f;
  #pragma unroll
  for (int kt = 0; kt < 8; ++kt) {
    int ko = kt * 16 + half * 8;
    short8 a = *(const short8*)&Ps[(w * 32 + m32) * 136 + ko];
    short8 bf = *(const short8*)&Vt[m32 * 136 + ko];
    ov = __builtin_amdgcn_mfma_f32_32x32x16_bf16(a, bf, ov, 0, 0, 0);
  }
  #pragma unroll
  for (int r = 0; r < 16; ++r) {
    int rowl = (r & 3) + 8 * (r >> 2) + 4 * half;
    int q = w * 32 + rowl;
    if (m32 < DH_ && q < S_)
      o[((size_t)(b * S_ + q)) * D_ + hh * DH_ + m32] =
          __float2bfloat16(ov[r] * rinv[r]);
  }
}

// ---------------------------------------------------------------------------
// out-proj + residual + LN (validated R5). 128 threads, BM=64 -> 200 blocks.
// ---------------------------------------------------------------------------
__global__ __launch_bounds__(128)
void outln_kernel(const __hip_bfloat16* __restrict__ A,
                  const __hip_bfloat16* __restrict__ Wt,
                  const float* __restrict__ bias,
                  const float* __restrict__ g, const float* __restrict__ bvec,
                  float* __restrict__ x, __hip_bfloat16* __restrict__ xb)
{
  __shared__ __align__(16) __hip_bfloat16 Asl[64 * 40];
  __shared__ __align__(16) __hip_bfloat16 Bsl[192 * 40];
  int tid = threadIdx.x, lane = tid & 63, w = tid >> 6;
  int m32 = lane & 31, half = lane >> 5;
  int bm = blockIdx.x * 64;

  floatx16 acc[6];
  #pragma unroll
  for (int nt = 0; nt < 6; ++nt)
    #pragma unroll
    for (int r = 0; r < 16; ++r) acc[nt][r] = 0.f;

  for (int k0 = 0; k0 < D_; k0 += 32) {
    {
      int r = tid >> 1, h = tid & 1;
      const float4* s = (const float4*)(A + (size_t)(bm + r) * D_ + k0 + h * 16);
      float4* d = (float4*)&Asl[r * 40 + h * 16];
      d[0] = s[0]; d[1] = s[1];
    }
    for (int e = tid; e < 384; e += 128) {
      int r = e >> 1, h = e & 1;
      const float4* s = (const float4*)(Wt + (size_t)r * D_ + k0 + h * 16);
      float4* d = (float4*)&Bsl[r * 40 + h * 16];
      d[0] = s[0]; d[1] = s[1];
    }
    __syncthreads();
    #pragma unroll
    for (int kc = 0; kc < 2; ++kc) {
      int ko = kc * 16 + half * 8;
      short8 a = *(const short8*)&Asl[(w * 32 + m32) * 40 + ko];
      #pragma unroll
      for (int nt = 0; nt < 6; ++nt) {
        short8 bf = *(const short8*)&Bsl[(nt * 32 + m32) * 40 + ko];
        acc[nt] = __builtin_amdgcn_mfma_f32_32x32x16_bf16(a, bf, acc[nt], 0, 0, 0);
      }
    }
    __syncthreads();
  }

  float cbias[6], cg[6], cb2[6];
  #pragma unroll
  for (int nt = 0; nt < 6; ++nt) {
    int col = nt * 32 + m32;
    cbias[nt] = bias[col]; cg[nt] = g[col]; cb2[nt] = bvec[col];
  }
  int rowbase = bm + w * 32 + 4 * half;
  #pragma unroll
  for (int r = 0; r < 16; ++r) {
    int row = rowbase + (r & 3) + 8 * (r >> 2);
    float part = 0.f;
    #pragma unroll
    for (int nt = 0; nt < 6; ++nt) {
      int col = nt * 32 + m32;
      float t = acc[nt][r] + cbias[nt] + x[(size_t)row * D_ + col];
      acc[nt][r] = t;
      part += t;
    }
    #pragma unroll
    for (int off = 1; off < 32; off <<= 1) part += __shfl_xor(part, off);
    float mean = part * (1.f / (float)D_);
    float sq = 0.f;
    #pragma unroll
    for (int nt = 0; nt < 6; ++nt) { float dd = acc[nt][r] - mean; sq += dd * dd; }
    #pragma unroll
    for (int off = 1; off < 32; off <<= 1) sq += __shfl_xor(sq, off);
    float inv = rsqrtf(sq * (1.f / (float)D_) + 1e-5f);
    #pragma unroll
    for (int nt = 0; nt < 6; ++nt) {
      int col = nt * 32 + m32;
      float ovv = (acc[nt][r] - mean) * inv * cg[nt] + cb2[nt];
      x[(size_t)row * D_ + col] = ovv;
      xb[(size_t)row * D_ + col] = __float2bfloat16(ovv);
    }
  }
}

// ---------------------------------------------------------------------------
// ff1 + ff2 + residual + LN (validated R4/R5). 256 threads, BM=64.
// ---------------------------------------------------------------------------
__global__ __launch_bounds__(256)
void ffln_kernel(const __hip_bfloat16* __restrict__ xbi,
                 const __hip_bfloat16* __restrict__ W1, const float* __restrict__ b1,
                 const __hip_bfloat16* __restrict__ W2, const float* __restrict__ b2,
                 const float* __restrict__ g, const float* __restrict__ bvec,
                 float* __restrict__ x, __hip_bfloat16* __restrict__ xb)
{
  __shared__ __align__(16) __hip_bfloat16 C1[64 * 260];
  __shared__ __align__(16) __hip_bfloat16 Asl[64 * 40];
  __shared__ __align__(16) __hip_bfloat16 Bsl[256 * 40];
  __shared__ float psum[64][2];
  __shared__ float psq[64][2];
  int tid = threadIdx.x, lane = tid & 63, w = tid >> 6;
  int m32 = lane & 31, half = lane >> 5;
  int mt = w & 1, ng = w >> 1;
  int bm = blockIdx.x * 64;

  floatx16 acc1[4];
  #pragma unroll
  for (int j = 0; j < 4; ++j)
    #pragma unroll
    for (int r = 0; r < 16; ++r) acc1[j][r] = 0.f;

  for (int k0 = 0; k0 < D_; k0 += 32) {
    if (tid < 128) {
      int r = tid >> 1, h = tid & 1;
      const float4* s = (const float4*)(xbi + (size_t)(bm + r) * D_ + k0 + h * 16);
      float4* d = (float4*)&Asl[r * 40 + h * 16];
      d[0] = s[0]; d[1] = s[1];
    }
    for (int e = tid; e < 512; e += 256) {
      int r = e >> 1, h = e & 1;
      const float4* s = (const float4*)(W1 + (size_t)r * D_ + k0 + h * 16);
      float4* d = (float4*)&Bsl[r * 40 + h * 16];
      d[0] = s[0]; d[1] = s[1];
    }
    __syncthreads();
    #pragma unroll
    for (int kc = 0; kc < 2; ++kc) {
      int ko = kc * 16 + half * 8;
      short8 a = *(const short8*)&Asl[(mt * 32 + m32) * 40 + ko];
      #pragma unroll
      for (int j = 0; j < 4; ++j) {
        short8 bf = *(const short8*)&Bsl[((ng * 4 + j) * 32 + m32) * 40 + ko];
        acc1[j] = __builtin_amdgcn_mfma_f32_32x32x16_bf16(a, bf, acc1[j], 0, 0, 0);
      }
    }
    __syncthreads();
  }
  {
    int rowb = mt * 32 + 4 * half;
    #pragma unroll
    for (int j = 0; j < 4; ++j) {
      int col = (ng * 4 + j) * 32 + m32;
      float cb = b1[col];
      #pragma unroll
      for (int r = 0; r < 16; ++r) {
        int row = rowb + (r & 3) + 8 * (r >> 2);
        C1[row * 260 + col] = __float2bfloat16(fmaxf(acc1[j][r] + cb, 0.f));
      }
    }
  }
  __syncthreads();

  floatx16 acc2[3];
  #pragma unroll
  for (int j = 0; j < 3; ++j)
    #pragma unroll
    for (int r = 0; r < 16; ++r) acc2[j][r] = 0.f;

  for (int k0 = 0; k0 < DFF_; k0 += 32) {
    for (int e = tid; e < 384; e += 256) {
      int r = e >> 1, h = e & 1;
      const float4* s = (const float4*)(W2 + (size_t)r * DFF_ + k0 + h * 16);
      float4* d = (float4*)&Bsl[r * 40 + h * 16];
      d[0] = s[0]; d[1] = s[1];
    }
    __syncthreads();
    #pragma unroll
    for (int kc = 0; kc < 2; ++kc) {
      int ko = kc * 16 + half * 8;
      const __hip_bfloat16* cp = &C1[(mt * 32 + m32) * 260 + k0 + ko];
      short8 a;
      {
        typedef short short4v __attribute__((ext_vector_type(4)));
        short4v lo = *(const short4v*)cp;
        short4v hi = *(const short4v*)(cp + 4);
        a[0]=lo[0]; a[1]=lo[1]; a[2]=lo[2]; a[3]=lo[3];
        a[4]=hi[0]; a[5]=hi[1]; a[6]=hi[2]; a[7]=hi[3];
      }
      #pragma unroll
      for (int j = 0; j < 3; ++j) {
        short8 bf = *(const short8*)&Bsl[((ng * 3 + j) * 32 + m32) * 40 + ko];
        acc2[j] = __builtin_amdgcn_mfma_f32_32x32x16_bf16(a, bf, acc2[j], 0, 0, 0);
      }
    }
    __syncthreads();
  }

  int rowb = mt * 32 + 4 * half;
  #pragma unroll
  for (int r = 0; r < 16; ++r) {
    int rl = rowb + (r & 3) + 8 * (r >> 2);
    int row = bm + rl;
    float p = 0.f;
    #pragma unroll
    for (int j = 0; j < 3; ++j) {
      int col = (ng * 3 + j) * 32 + m32;
      float t = acc2[j][r] + b2[col] + x[(size_t)row * D_ + col];
      acc2[j][r] = t;
      p += t;
    }
    #pragma unroll
    for (int off = 1; off < 32; off <<= 1) p += __shfl_xor(p, off);
    if (m32 == 0) psum[rl][ng] = p;
  }
  __syncthreads();
  float mean[16];
  #pragma unroll
  for (int r = 0; r < 16; ++r) {
    int rl = rowb + (r & 3) + 8 * (r >> 2);
    mean[r] = (psum[rl][0] + psum[rl][1]) * (1.f / (float)D_);
  }
  #pragma unroll
  for (int r = 0; r < 16; ++r) {
    int rl = rowb + (r & 3) + 8 * (r >> 2);
    float s = 0.f;
    #pragma unroll
    for (int j = 0; j < 3; ++j) { float dd = acc2[j][r] - mean[r]; s += dd * dd; }
    #pragma unroll
    for (int off = 1; off < 32; off <<= 1) s += __shfl_xor(s, off);
    if (m32 == 0) psq[rl][ng] = s;
  }
  __syncthreads();
  #pragma unroll
  for (int r = 0; r < 16; ++r) {
    int rl = rowb + (r & 3) + 8 * (r >> 2);
    int row = bm + rl;
    float inv = rsqrtf((psq[rl][0] + psq[rl][1]) * (1.f / (float)D_) + 1e-5f);
    #pragma unroll
    for (int j = 0; j < 3; ++j) {
      int col = (ng * 3 + j) * 32 + m32;
      float ovv = (acc2[j][r] - mean[r]) * inv * g[col] + bvec[col];
      x[(size_t)row * D_ + col] = ovv;
      xb[(size_t)row * D_ + col] = __float2bfloat16(ovv);
    }
  }
}

// ---------------------------------------------------------------------------
// Head (fp32): one block per (w,b) slot.
// ---------------------------------------------------------------------------
__global__ __launch_bounds__(256)
void head_kernel(const float* __restrict__ x, const float* __restrict__ noise,
                 const float* __restrict__ pw1, const float* __restrict__ pb1,
                 const float* __restrict__ pw2, const float* __restrict__ pb2,
                 const float* __restrict__ ew1, const float* __restrict__ eb1,
                 const float* __restrict__ ew2, const float* __restrict__ eb2,
                 float* __restrict__ out)
{
  int idx = blockIdx.x;
  int b = idx & 127, w = idx >> 7;
  int tid = threadIdx.x;
  __shared__ float slot[192];
  __shared__ float ph[256];
  __shared__ float eh[128];
  if (tid < 192)
    slot[tid] = x[((size_t)b * S_ + (S_ - 1)) * D_ + tid]
              + noise[((size_t)w * B_ + b) * D_ + tid] * 0.1f;
  __syncthreads();
  {
    const float4* wr = (const float4*)(pw1 + (size_t)tid * D_);
    const float4* sp = (const float4*)slot;
    float a = pb1[tid];
    #pragma unroll 12
    for (int k = 0; k < 48; ++k) {
      float4 wv = wr[k], sv = sp[k];
      a += wv.x*sv.x + wv.y*sv.y + wv.z*sv.z + wv.w*sv.w;
    }
    ph[tid] = fmaxf(a, 0.f);
  }
  if (tid < 128) {
    const float4* wr = (const float4*)(ew1 + (size_t)tid * D_);
    const float4* sp = (const float4*)slot;
    float a = eb1[tid];
    #pragma unroll 12
    for (int k = 0; k < 48; ++k) {
      float4 wv = wr[k], sv = sp[k];
      a += wv.x*sv.x + wv.y*sv.y + wv.z*sv.z + wv.w*sv.w;
    }
    eh[tid] = fmaxf(a, 0.f);
  }
  __syncthreads();
  if (tid < 4) {
    float a = pb2[tid];
    const float4* wr = (const float4*)(pw2 + tid * 256);
    const float4* pp = (const float4*)ph;
    for (int k = 0; k < 64; ++k) {
      float4 wv = wr[k], pv = pp[k];
      a += wv.x*pv.x + wv.y*pv.y + wv.z*pv.z + wv.w*pv.w;
    }
    out[((size_t)b * W_ + w) * 4 + tid] = a;
  }
  if (tid == 4) {
    float a = eb2[0];
    const float4* wr = (const float4*)ew2;
    const float4* pp = (const float4*)eh;
    for (int k = 0; k < 32; ++k) {
      float4 wv = wr[k], pv = pp[k];
      a += wv.x*pv.x + wv.y*pv.y + wv.z*pv.z + wv.w*pv.w;
    }
    out[(size_t)B_ * W_ * 4 + (size_t)b * W_ + w] = 1.f / (1.f + expf(-a));
  }
}

// ---------------------------------------------------------------------------
extern "C" void kernel_launch(void* const* d_in, const int* in_sizes, int n_in,
                              void* d_out, int out_size, void* d_ws, size_t ws_size,
                              hipStream_t stream)
{
  const int*   title_idx       = (const int*)  d_in[0];
  const int*   class_idx       = (const int*)  d_in[1];
  const int*   process_idx     = (const int*)  d_in[2];
  const int*   activity_type   = (const int*)  d_in[3];
  const float* mouse_pos       = (const float*)d_in[4];
  const float* rect            = (const float*)d_in[5];
  const float* flags           = (const float*)d_in[6];
  const float* keyboard_active = (const float*)d_in[7];
  const float* window_mask     = (const float*)d_in[8];
  const float* noise           = (const float*)d_in[9];
  const float* title_emb       = (const float*)d_in[10];
  const float* class_emb       = (const float*)d_in[11];
  const float* process_emb     = (const float*)d_in[12];
  const float* spatial_w1      = (const float*)d_in[13];
  const float* spatial_b1      = (const float*)d_in[14];
  const float* spatial_w2      = (const float*)d_in[15];
  const float* spatial_b2      = (const float*)d_in[16];
  const float* wfuse_w         = (const float*)d_in[17];
  const float* wfuse_b         = (const float*)d_in[18];
  const float* mouse_w1        = (const float*)d_in[19];
  const float* mouse_b1        = (const float*)d_in[20];
  const float* mouse_w2        = (const float*)d_in[21];
  const float* mouse_b2        = (const float*)d_in[22];
  const float* act_emb         = (const float*)d_in[23];
  const float* kbd_w           = (const float*)d_in[24];
  const float* kbd_b           = (const float*)d_in[25];
  const float* afuse_w         = (const float*)d_in[26];
  const float* afuse_b         = (const float*)d_in[27];
  const float* qkv_w           = (const float*)d_in[28];
  const float* qkv_b           = (const float*)d_in[29];
  const float* out_w           = (const float*)d_in[30];
  const float* out_b           = (const float*)d_in[31];
  const float* ff1_w           = (const float*)d_in[32];
  const float* ff1_b           = (const float*)d_in[33];
  const float* ff2_w           = (const float*)d_in[34];
  const float* ff2_b           = (const float*)d_in[35];
  const float* ln1_g           = (const float*)d_in[36];
  const float* ln1_b           = (const float*)d_in[37];
  const float* ln2_g           = (const float*)d_in[38];
  const float* ln2_b           = (const float*)d_in[39];
  const float* proj_w1         = (const float*)d_in[40];
  const float* proj_b1         = (const float*)d_in[41];
  const float* proj_w2         = (const float*)d_in[42];
  const float* proj_b2         = (const float*)d_in[43];
  const float* ex_w1           = (const float*)d_in[44];
  const float* ex_b1           = (const float*)d_in[45];
  const float* ex_w2           = (const float*)d_in[46];
  const float* ex_b2           = (const float*)d_in[47];

  float* out = (float*)d_out;

  // workspace layout
  float* x = (float*)d_ws;                                      // BS*192 f32
  __hip_bfloat16* xb   = (__hip_bfloat16*)(x + (size_t)BS_ * D_);
  __hip_bfloat16* attb = xb   + (size_t)BS_ * D_;
  __hip_bfloat16* wqb  = attb + (size_t)BS_ * D_;               // 6*576*192
  __hip_bfloat16* wob  = wqb  + (size_t)L_ * THREED_ * D_;      // 6*192*192
  __hip_bfloat16* wf1b = wob  + (size_t)L_ * D_ * D_;           // 6*256*192
  __hip_bfloat16* wf2b = wf1b + (size_t)L_ * DFF_ * D_;         // 6*192*256
  float* TE2  = (float*)(wf2b + (size_t)L_ * D_ * DFF_);        // 1000*128
  float* CE2  = TE2  + 1000 * 128;                              // 500*128
  float* PE2  = CE2  + 500 * 128;                               // 1000*128
  float* WSPt = PE2  + 1000 * 128;                              // 64*128
  float* wfb2 = WSPt + 64 * 128;                                // 128
  (void)ws_size; (void)n_in; (void)in_sizes; (void)out_size;

  convertprep_kernel<<<2003, 256, 0, stream>>>(
      qkv_w, wqb, out_w, wob, ff1_w, wf1b, ff2_w, wf2b,
      title_emb, class_emb, process_emb, wfuse_w, wfuse_b,
      spatial_w2, spatial_b2, TE2, CE2, PE2, WSPt, wfb2);

  encode3_kernel<<<BS_ / 2, 256, 0, stream>>>(
      title_idx, class_idx, process_idx, activity_type, mouse_pos, rect, flags,
      keyboard_active, window_mask, spatial_w1, spatial_b1,
      TE2, CE2, PE2, WSPt, wfb2,
      mouse_w1, mouse_b1, mouse_w2, mouse_b2, act_emb, kbd_w, kbd_b,
      afuse_w, afuse_b, x, xb);

  for (int l = 0; l < L_; ++l) {
    qkvattn_kernel<<<B_ * H_, 256, 0, stream>>>(
        xb, wqb + (size_t)l * THREED_ * D_, qkv_b + (size_t)l * THREED_, attb);
    outln_kernel<<<BS_ / 64, 128, 0, stream>>>(
        attb, wob + (size_t)l * D_ * D_, out_b + (size_t)l * D_,
        ln1_g + (size_t)l * D_, ln1_b + (size_t)l * D_, x, xb);
    ffln_kernel<<<BS_ / 64, 256, 0, stream>>>(
        xb, wf1b + (size_t)l * DFF_ * D_, ff1_b + (size_t)l * DFF_,
        wf2b + (size_t)l * D_ * DFF_, ff2_b + (size_t)l * D_,
        ln2_g + (size_t)l * D_, ln2_b + (size_t)l * D_, x, xb);
  }

  head_kernel<<<W_ * B_, 256, 0, stream>>>(
      x, noise, proj_w1, proj_b1, proj_w2, proj_b2,
      ex_w1, ex_b1, ex_w2, ex_b2, out);
}